// Round 1
// baseline (980.268 us; speedup 1.0000x reference)
//
#include <hip/hip_runtime.h>

#define NN 50000
#define NBGRAPH 512
#define DIN 768
#define DHID 256
#define DOUT 128

__device__ __forceinline__ float lrelu(float v) { return v > 0.f ? v : 0.2f * v; }

// ---------------- CSR build ----------------
__global__ void k_zero2(int* __restrict__ a, int* __restrict__ b, int n) {
  int i = blockIdx.x * blockDim.x + threadIdx.x;
  if (i < n) { a[i] = 0; b[i] = 0; }
}

__global__ void k_hist(const int* __restrict__ ei, int* __restrict__ deg, int E, int Etot) {
  int e = blockIdx.x * blockDim.x + threadIdx.x;
  if (e >= Etot) return;
  int dst = (e < E) ? ei[e] : (e - E);   // dst = edge_index[0]; self-loops appended
  atomicAdd(&deg[dst], 1);
}

__global__ __launch_bounds__(1024) void k_exscan(const int* __restrict__ deg, int* __restrict__ off, int n) {
  __shared__ int sh[1024];
  int tid = threadIdx.x;
  int carry = 0;
  int nchunk = (n + 1023) / 1024;
  for (int c = 0; c < nchunk; ++c) {
    int i = c * 1024 + tid;
    int v = (i < n) ? deg[i] : 0;
    sh[tid] = v;
    __syncthreads();
    for (int d = 1; d < 1024; d <<= 1) {
      int t = (tid >= d) ? sh[tid - d] : 0;
      __syncthreads();
      sh[tid] += t;
      __syncthreads();
    }
    if (i < n) off[i] = carry + sh[tid] - v;   // exclusive
    carry += sh[1023];
    __syncthreads();
  }
  if (tid == 0) off[n] = carry;
}

__global__ void k_scatter(const int* __restrict__ ei, const int* __restrict__ off,
                          int* __restrict__ cur, int* __restrict__ csr, int E, int Etot) {
  int e = blockIdx.x * blockDim.x + threadIdx.x;
  if (e >= Etot) return;
  int dst, src;
  if (e < E) { dst = ei[e]; src = ei[E + e]; }   // src = edge_index[1]
  else       { dst = src = e - E; }
  int p = atomicAdd(&cur[dst], 1);
  csr[off[dst] + p] = src;
}

// ---------------- roots / segments ----------------
__global__ void k_segstart(const int* __restrict__ batch, int* __restrict__ segstart, int n, int b_cnt) {
  int b = blockIdx.x * blockDim.x + threadIdx.x;
  if (b > b_cnt) return;
  int lo = 0, hi = n;
  while (lo < hi) { int mid = (lo + hi) >> 1; if (batch[mid] < b) lo = mid + 1; else hi = mid; }
  segstart[b] = lo;
}

__global__ void k_rootn(const int* __restrict__ batch, const int* __restrict__ segstart,
                        int* __restrict__ rootn, int n) {
  int i = blockIdx.x * blockDim.x + threadIdx.x;
  if (i < n) rootn[i] = segstart[batch[i]];
}

// ---------------- GEMM1: H1 = x @ W1  (M=NN, K=768, N=256) ----------------
__global__ __launch_bounds__(256) void k_gemm1(const float* __restrict__ A,
                                               const float* __restrict__ B,
                                               float* __restrict__ C) {
  const int M = NN, K = DIN, NC = DHID;
  __shared__ float As[16][68];
  __shared__ float Bs[16][68];
  const int tid = threadIdx.x;
  const int bm = blockIdx.x * 64;
  const int bn = blockIdx.y * 64;
  const int tx = tid & 15, ty = tid >> 4;
  const int arow = tid >> 2, akq = (tid & 3) * 4;
  const int brow = tid >> 4, bcol = (tid & 15) * 4;
  const int gr = bm + arow;
  float acc[4][4] = {};
  for (int k0 = 0; k0 < K; k0 += 16) {
    float4 av = make_float4(0.f, 0.f, 0.f, 0.f);
    if (gr < M) av = *(const float4*)&A[(size_t)gr * K + k0 + akq];
    As[akq + 0][arow] = av.x; As[akq + 1][arow] = av.y;
    As[akq + 2][arow] = av.z; As[akq + 3][arow] = av.w;
    *(float4*)&Bs[brow][bcol] = *(const float4*)&B[(size_t)(k0 + brow) * NC + bn + bcol];
    __syncthreads();
#pragma unroll
    for (int k = 0; k < 16; ++k) {
      float4 a = *(const float4*)&As[k][ty * 4];
      float4 b = *(const float4*)&Bs[k][tx * 4];
      acc[0][0] += a.x * b.x; acc[0][1] += a.x * b.y; acc[0][2] += a.x * b.z; acc[0][3] += a.x * b.w;
      acc[1][0] += a.y * b.x; acc[1][1] += a.y * b.y; acc[1][2] += a.y * b.z; acc[1][3] += a.y * b.w;
      acc[2][0] += a.z * b.x; acc[2][1] += a.z * b.y; acc[2][2] += a.z * b.z; acc[2][3] += a.z * b.w;
      acc[3][0] += a.w * b.x; acc[3][1] += a.w * b.y; acc[3][2] += a.w * b.z; acc[3][3] += a.w * b.w;
    }
    __syncthreads();
  }
  const int row0 = bm + ty * 4, col0 = bn + tx * 4;
#pragma unroll
  for (int i = 0; i < 4; ++i)
    if (row0 + i < M)
      *(float4*)&C[(size_t)(row0 + i) * NC + col0] =
          make_float4(acc[i][0], acc[i][1], acc[i][2], acc[i][3]);
}

// ---------------- GEMM2: H2 = relu(concat(OUT1, x[root])) @ W2 (M=NN, K=1024, N=128) ----------------
__global__ __launch_bounds__(256) void k_gemm2(const float* __restrict__ OUT1,
                                               const float* __restrict__ X,
                                               const int* __restrict__ rootn,
                                               const float* __restrict__ B,
                                               float* __restrict__ C) {
  const int M = NN, K = DHID + DIN, NC = DOUT;
  __shared__ float As[16][68];
  __shared__ float Bs[16][68];
  const int tid = threadIdx.x;
  const int bm = blockIdx.x * 64;
  const int bn = blockIdx.y * 64;
  const int tx = tid & 15, ty = tid >> 4;
  const int arow = tid >> 2, akq = (tid & 3) * 4;
  const int brow = tid >> 4, bcol = (tid & 15) * 4;
  const int gr = bm + arow;
  int rn = 0;
  if (gr < M) rn = rootn[gr];
  float acc[4][4] = {};
  for (int k0 = 0; k0 < K; k0 += 16) {
    float4 av = make_float4(0.f, 0.f, 0.f, 0.f);
    if (gr < M) {
      int kk = k0 + akq;
      if (kk < DHID) av = *(const float4*)&OUT1[(size_t)gr * DHID + kk];
      else           av = *(const float4*)&X[(size_t)rn * DIN + (kk - DHID)];
      av.x = fmaxf(av.x, 0.f); av.y = fmaxf(av.y, 0.f);
      av.z = fmaxf(av.z, 0.f); av.w = fmaxf(av.w, 0.f);
    }
    As[akq + 0][arow] = av.x; As[akq + 1][arow] = av.y;
    As[akq + 2][arow] = av.z; As[akq + 3][arow] = av.w;
    *(float4*)&Bs[brow][bcol] = *(const float4*)&B[(size_t)(k0 + brow) * NC + bn + bcol];
    __syncthreads();
#pragma unroll
    for (int k = 0; k < 16; ++k) {
      float4 a = *(const float4*)&As[k][ty * 4];
      float4 b = *(const float4*)&Bs[k][tx * 4];
      acc[0][0] += a.x * b.x; acc[0][1] += a.x * b.y; acc[0][2] += a.x * b.z; acc[0][3] += a.x * b.w;
      acc[1][0] += a.y * b.x; acc[1][1] += a.y * b.y; acc[1][2] += a.y * b.z; acc[1][3] += a.y * b.w;
      acc[2][0] += a.z * b.x; acc[2][1] += a.z * b.y; acc[2][2] += a.z * b.z; acc[2][3] += a.z * b.w;
      acc[3][0] += a.w * b.x; acc[3][1] += a.w * b.y; acc[3][2] += a.w * b.z; acc[3][3] += a.w * b.w;
    }
    __syncthreads();
  }
  const int row0 = bm + ty * 4, col0 = bn + tx * 4;
#pragma unroll
  for (int i = 0; i < 4; ++i)
    if (row0 + i < M)
      *(float4*)&C[(size_t)(row0 + i) * NC + col0] =
          make_float4(acc[i][0], acc[i][1], acc[i][2], acc[i][3]);
}

// ---------------- attention scores, layer 1 (D=64, F=256) ----------------
__global__ __launch_bounds__(256) void k_scores1(const float* __restrict__ H,
                                                 const float* __restrict__ att_s,
                                                 const float* __restrict__ att_d,
                                                 float4* __restrict__ as_out,
                                                 float4* __restrict__ ad_out) {
  int lane = threadIdx.x & 63;
  int n = blockIdx.x * 4 + (threadIdx.x >> 6);
  if (n >= NN) return;
  float s[4], d[4];
#pragma unroll
  for (int h = 0; h < 4; ++h) {
    float hv = H[(size_t)n * DHID + h * 64 + lane];
    s[h] = hv * att_s[h * 64 + lane];
    d[h] = hv * att_d[h * 64 + lane];
  }
#pragma unroll
  for (int m = 1; m < 64; m <<= 1) {
#pragma unroll
    for (int h = 0; h < 4; ++h) {
      s[h] += __shfl_xor(s[h], m);
      d[h] += __shfl_xor(d[h], m);
    }
  }
  if (lane == 0) {
    as_out[n] = make_float4(s[0], s[1], s[2], s[3]);
    ad_out[n] = make_float4(d[0], d[1], d[2], d[3]);
  }
}

// ---------------- attention scores, layer 2 (D=32, F=128) ----------------
__global__ __launch_bounds__(256) void k_scores2(const float* __restrict__ H,
                                                 const float* __restrict__ att_s,
                                                 const float* __restrict__ att_d,
                                                 float4* __restrict__ as_out,
                                                 float4* __restrict__ ad_out) {
  int lane = threadIdx.x & 63;
  int n = blockIdx.x * 4 + (threadIdx.x >> 6);
  if (n >= NN) return;
  float s0, s1, d0, d1;
  {
    float hv0 = H[(size_t)n * DOUT + lane];
    float hv1 = H[(size_t)n * DOUT + 64 + lane];
    s0 = hv0 * att_s[lane];       d0 = hv0 * att_d[lane];
    s1 = hv1 * att_s[64 + lane];  d1 = hv1 * att_d[64 + lane];
  }
#pragma unroll
  for (int m = 1; m < 32; m <<= 1) {
    s0 += __shfl_xor(s0, m); s1 += __shfl_xor(s1, m);
    d0 += __shfl_xor(d0, m); d1 += __shfl_xor(d1, m);
  }
  float s0o = __shfl_xor(s0, 32), s1o = __shfl_xor(s1, 32);
  float d0o = __shfl_xor(d0, 32), d1o = __shfl_xor(d1, 32);
  if (lane == 0) {
    as_out[n] = make_float4(s0, s0o, s1, s1o);
    ad_out[n] = make_float4(d0, d0o, d1, d1o);
  }
}

// ---------------- GAT aggregation, layer 1 (heads=4, D=64) ----------------
__global__ __launch_bounds__(256) void k_agg1(const int* __restrict__ off, const int* __restrict__ csr,
                                              const float4* __restrict__ as_v, const float4* __restrict__ ad_v,
                                              const float* __restrict__ H, const float* __restrict__ bias,
                                              float* __restrict__ OUT) {
  int lane = threadIdx.x & 63;
  int n = blockIdx.x * 4 + (threadIdx.x >> 6);
  if (n >= NN) return;
  int beg = off[n], end = off[n + 1];
  float4 adv = ad_v[n];
  float ad_[4] = {adv.x, adv.y, adv.z, adv.w};
  float mx[4] = {-INFINITY, -INFINITY, -INFINITY, -INFINITY};
  for (int e = beg + lane; e < end; e += 64) {
    float4 a = as_v[csr[e]];
    mx[0] = fmaxf(mx[0], a.x); mx[1] = fmaxf(mx[1], a.y);
    mx[2] = fmaxf(mx[2], a.z); mx[3] = fmaxf(mx[3], a.w);
  }
#pragma unroll
  for (int m = 1; m < 64; m <<= 1)
#pragma unroll
    for (int h = 0; h < 4; ++h) mx[h] = fmaxf(mx[h], __shfl_xor(mx[h], m));
  float emax[4];
#pragma unroll
  for (int h = 0; h < 4; ++h) emax[h] = lrelu(mx[h] + ad_[h]);
  float den[4] = {0.f, 0.f, 0.f, 0.f};
  for (int e = beg + lane; e < end; e += 64) {
    float4 a = as_v[csr[e]];
    float aa[4] = {a.x, a.y, a.z, a.w};
#pragma unroll
    for (int h = 0; h < 4; ++h) den[h] += __expf(lrelu(aa[h] + ad_[h]) - emax[h]);
  }
#pragma unroll
  for (int m = 1; m < 64; m <<= 1)
#pragma unroll
    for (int h = 0; h < 4; ++h) den[h] += __shfl_xor(den[h], m);
  float rden[4];
#pragma unroll
  for (int h = 0; h < 4; ++h) rden[h] = 1.f / (den[h] + 1e-16f);
  float acc[4] = {0.f, 0.f, 0.f, 0.f};
  for (int e = beg; e < end; ++e) {
    int s = csr[e];
    float4 a = as_v[s];
    float aa[4] = {a.x, a.y, a.z, a.w};
    float al[4];
#pragma unroll
    for (int h = 0; h < 4; ++h) al[h] = __expf(lrelu(aa[h] + ad_[h]) - emax[h]) * rden[h];
    const float* hr = &H[(size_t)s * DHID];
#pragma unroll
    for (int j = 0; j < 4; ++j) acc[j] += al[j] * hr[j * 64 + lane];
  }
#pragma unroll
  for (int j = 0; j < 4; ++j)
    OUT[(size_t)n * DHID + j * 64 + lane] = acc[j] + bias[j * 64 + lane];
}

// ---------------- GAT aggregation, layer 2 (heads=4, D=32) ----------------
__global__ __launch_bounds__(256) void k_agg2(const int* __restrict__ off, const int* __restrict__ csr,
                                              const float4* __restrict__ as_v, const float4* __restrict__ ad_v,
                                              const float* __restrict__ H, const float* __restrict__ bias,
                                              float* __restrict__ OUT) {
  int lane = threadIdx.x & 63;
  int n = blockIdx.x * 4 + (threadIdx.x >> 6);
  if (n >= NN) return;
  int beg = off[n], end = off[n + 1];
  float4 adv = ad_v[n];
  float ad_[4] = {adv.x, adv.y, adv.z, adv.w};
  float mx[4] = {-INFINITY, -INFINITY, -INFINITY, -INFINITY};
  for (int e = beg + lane; e < end; e += 64) {
    float4 a = as_v[csr[e]];
    mx[0] = fmaxf(mx[0], a.x); mx[1] = fmaxf(mx[1], a.y);
    mx[2] = fmaxf(mx[2], a.z); mx[3] = fmaxf(mx[3], a.w);
  }
#pragma unroll
  for (int m = 1; m < 64; m <<= 1)
#pragma unroll
    for (int h = 0; h < 4; ++h) mx[h] = fmaxf(mx[h], __shfl_xor(mx[h], m));
  float emax[4];
#pragma unroll
  for (int h = 0; h < 4; ++h) emax[h] = lrelu(mx[h] + ad_[h]);
  float den[4] = {0.f, 0.f, 0.f, 0.f};
  for (int e = beg + lane; e < end; e += 64) {
    float4 a = as_v[csr[e]];
    float aa[4] = {a.x, a.y, a.z, a.w};
#pragma unroll
    for (int h = 0; h < 4; ++h) den[h] += __expf(lrelu(aa[h] + ad_[h]) - emax[h]);
  }
#pragma unroll
  for (int m = 1; m < 64; m <<= 1)
#pragma unroll
    for (int h = 0; h < 4; ++h) den[h] += __shfl_xor(den[h], m);
  float rden[4];
#pragma unroll
  for (int h = 0; h < 4; ++h) rden[h] = 1.f / (den[h] + 1e-16f);

  int h0 = lane >> 5;  // head of feature f=lane is h0; of f=64+lane is 2+h0
  float adA = h0 ? ad_[1] : ad_[0];
  float adB = h0 ? ad_[3] : ad_[2];
  float emA = h0 ? emax[1] : emax[0];
  float emB = h0 ? emax[3] : emax[2];
  float rdA = h0 ? rden[1] : rden[0];
  float rdB = h0 ? rden[3] : rden[2];
  float acc0 = 0.f, acc1 = 0.f;
  for (int e = beg; e < end; ++e) {
    int s = csr[e];
    float4 a = as_v[s];
    float aA = h0 ? a.y : a.x;
    float aB = h0 ? a.w : a.z;
    float alA = __expf(lrelu(aA + adA) - emA) * rdA;
    float alB = __expf(lrelu(aB + adB) - emB) * rdB;
    const float* hr = &H[(size_t)s * DOUT];
    acc0 += alA * hr[lane];
    acc1 += alB * hr[64 + lane];
  }
  OUT[(size_t)n * DOUT + lane] = acc0 + bias[lane];
  OUT[(size_t)n * DOUT + 64 + lane] = acc1 + bias[64 + lane];
}

// ---------------- pooling ----------------
__global__ __launch_bounds__(256) void k_pool(const int* __restrict__ segstart,
                                              const float* __restrict__ OUT2,
                                              const float* __restrict__ OUT1,
                                              float* __restrict__ out) {
  int b = blockIdx.x;
  int t = threadIdx.x;
  int s = segstart[b], e = segstart[b + 1];
  float* ob = out + (size_t)b * 384;
  if (s >= e) {
    for (int i = t; i < 384; i += 256) ob[i] = 0.f;
    return;
  }
  if (t < 128) {
    float sum = 0.f;
    for (int n = s; n < e; ++n) {
      float v = OUT2[(size_t)n * DOUT + t];
      sum += v > 0.f ? v : 0.f;
    }
    ob[t] = sum / (float)(e - s);
  } else {
    int k = t - 128;
    ob[128 + k] = OUT1[(size_t)s * DHID + k];          // re2 = OUT1[root]
    ob[256 + k] = OUT1[(size_t)s * DHID + 128 + k];
  }
}

// ---------------- launch ----------------
extern "C" void kernel_launch(void* const* d_in, const int* in_sizes, int n_in,
                              void* d_out, int out_size, void* d_ws, size_t ws_size,
                              hipStream_t stream) {
  const float* x    = (const float*)d_in[0];
  const int*   ei   = (const int*)d_in[1];
  const int*   batch = (const int*)d_in[2];
  const float* W1   = (const float*)d_in[3];
  const float* as1w = (const float*)d_in[4];
  const float* ad1w = (const float*)d_in[5];
  const float* b1   = (const float*)d_in[6];
  const float* W2   = (const float*)d_in[7];
  const float* as2w = (const float*)d_in[8];
  const float* ad2w = (const float*)d_in[9];
  const float* b2   = (const float*)d_in[10];
  float* out = (float*)d_out;
  char* ws = (char*)d_ws;

  const int E = in_sizes[1] / 2;
  const int Etot = E + NN;

  // workspace layout (bytes)
  float*  H1   = (float*)(ws + 0);            // NN*256*4 = 51.2 MB; later reused:
  float*  H2   = (float*)(ws + 0);            //   NN*128*4 = 25.6 MB
  float*  OUT2 = (float*)(ws + 25600000);     //   NN*128*4 = 25.6 MB
  float*  OUT1 = (float*)(ws + 51200000);     // NN*256*4 = 51.2 MB
  float4* as1  = (float4*)(ws + 102400000);   // 0.8 MB
  float4* ad1  = (float4*)(ws + 103200000);
  float4* as2  = (float4*)(ws + 104000000);
  float4* ad2  = (float4*)(ws + 104800000);
  int* deg     = (int*)(ws + 105600000);      // NN
  int* cur     = (int*)(ws + 105800000);      // NN
  int* off     = (int*)(ws + 106000000);      // NN+1
  int* csr     = (int*)(ws + 106200016);      // Etot
  int* segstart = (int*)(ws + 109600016);     // NBGRAPH+1
  int* rootn   = (int*)(ws + 109602080);      // NN

  const int TB = 256;

  // CSR build + segments
  k_zero2<<<(NN + TB - 1) / TB, TB, 0, stream>>>(deg, cur, NN);
  k_hist<<<(Etot + TB - 1) / TB, TB, 0, stream>>>(ei, deg, E, Etot);
  k_exscan<<<1, 1024, 0, stream>>>(deg, off, NN);
  k_scatter<<<(Etot + TB - 1) / TB, TB, 0, stream>>>(ei, off, cur, csr, E, Etot);
  k_segstart<<<(NBGRAPH + 1 + TB - 1) / TB, TB, 0, stream>>>(batch, segstart, NN, NBGRAPH);
  k_rootn<<<(NN + TB - 1) / TB, TB, 0, stream>>>(batch, segstart, rootn, NN);

  // layer 1
  dim3 g1((NN + 63) / 64, DHID / 64);
  k_gemm1<<<g1, TB, 0, stream>>>(x, W1, H1);
  k_scores1<<<(NN + 3) / 4, TB, 0, stream>>>(H1, as1w, ad1w, as1, ad1);
  k_agg1<<<(NN + 3) / 4, TB, 0, stream>>>(off, csr, as1, ad1, H1, b1, OUT1);

  // layer 2 (H1 region is now dead; H2/OUT2 alias it)
  dim3 g2((NN + 63) / 64, DOUT / 64);
  k_gemm2<<<g2, TB, 0, stream>>>(OUT1, x, rootn, W2, H2);
  k_scores2<<<(NN + 3) / 4, TB, 0, stream>>>(H2, as2w, ad2w, as2, ad2);
  k_agg2<<<(NN + 3) / 4, TB, 0, stream>>>(off, csr, as2, ad2, H2, b2, OUT2);

  // pool
  k_pool<<<NBGRAPH, TB, 0, stream>>>(segstart, OUT2, OUT1, out);
}

// Round 2
// 613.675 us; speedup vs baseline: 1.5974x; 1.5974x over previous
//
#include <hip/hip_runtime.h>

#define NN 50000
#define NBGRAPH 512
#define DIN 768
#define DHID 256
#define DOUT 128

typedef unsigned short ushort_t;
typedef __attribute__((ext_vector_type(8))) short bf16x8;
typedef __attribute__((ext_vector_type(4))) float f32x4;

__device__ __forceinline__ float lrelu(float v) { return v > 0.f ? v : 0.2f * v; }

__device__ __forceinline__ ushort_t f2bf(float f) {
  unsigned int u = __builtin_bit_cast(unsigned int, f);
  u += 0x7fffu + ((u >> 16) & 1u);
  return (ushort_t)(u >> 16);
}

// ---------------- CSR build ----------------
__global__ void k_zero2(int* __restrict__ a, int* __restrict__ b, int n) {
  int i = blockIdx.x * blockDim.x + threadIdx.x;
  if (i < n) { a[i] = 0; b[i] = 0; }
}

__global__ void k_hist(const int* __restrict__ ei, int* __restrict__ deg, int E, int Etot) {
  int e = blockIdx.x * blockDim.x + threadIdx.x;
  if (e >= Etot) return;
  int dst = (e < E) ? ei[e] : (e - E);
  atomicAdd(&deg[dst], 1);
}

__global__ __launch_bounds__(1024) void k_exscan(const int* __restrict__ deg, int* __restrict__ off, int n) {
  __shared__ int sh[1024];
  int tid = threadIdx.x;
  int carry = 0;
  int nchunk = (n + 1023) / 1024;
  for (int c = 0; c < nchunk; ++c) {
    int i = c * 1024 + tid;
    int v = (i < n) ? deg[i] : 0;
    sh[tid] = v;
    __syncthreads();
    for (int d = 1; d < 1024; d <<= 1) {
      int t = (tid >= d) ? sh[tid - d] : 0;
      __syncthreads();
      sh[tid] += t;
      __syncthreads();
    }
    if (i < n) off[i] = carry + sh[tid] - v;
    carry += sh[1023];
    __syncthreads();
  }
  if (tid == 0) off[n] = carry;
}

__global__ void k_scatter(const int* __restrict__ ei, const int* __restrict__ off,
                          int* __restrict__ cur, int* __restrict__ csr, int E, int Etot) {
  int e = blockIdx.x * blockDim.x + threadIdx.x;
  if (e >= Etot) return;
  int dst, src;
  if (e < E) { dst = ei[e]; src = ei[E + e]; }
  else       { dst = src = e - E; }
  int p = atomicAdd(&cur[dst], 1);
  csr[off[dst] + p] = src;
}

// ---------------- roots / segments ----------------
__global__ void k_segstart(const int* __restrict__ batch, int* __restrict__ segstart, int n, int b_cnt) {
  int b = blockIdx.x * blockDim.x + threadIdx.x;
  if (b > b_cnt) return;
  int lo = 0, hi = n;
  while (lo < hi) { int mid = (lo + hi) >> 1; if (batch[mid] < b) lo = mid + 1; else hi = mid; }
  segstart[b] = lo;
}

__global__ void k_rootn(const int* __restrict__ batch, const int* __restrict__ segstart,
                        int* __restrict__ rootn, int n) {
  int i = blockIdx.x * blockDim.x + threadIdx.x;
  if (i < n) rootn[i] = segstart[batch[i]];
}

// ---------------- weight transpose+cast: Wt[n][k] = bf16(W[k][n]) ----------------
__global__ void k_prepW(const float* __restrict__ W, ushort_t* __restrict__ Wt, int K, int N) {
  int id = blockIdx.x * blockDim.x + threadIdx.x;
  if (id >= K * N) return;
  int n = id / K, k = id - n * K;
  Wt[(size_t)n * K + k] = f2bf(W[(size_t)k * N + n]);
}

// ---------------- MFMA GEMM1: H1 = bf16(x) @ bf16(W1)  (M=NN, K=768, N=256) ----------------
// A: f32 [NN][768] cast on the fly.  Bt: bf16 [256][768] (pre-transposed W1).
#define LDT 40  // padded LDS row stride in bf16 elems (80 B, 16B-aligned, ~2-way banks)
__global__ __launch_bounds__(256) void k_gemm1m(const float* __restrict__ A,
                                                const ushort_t* __restrict__ Bt,
                                                float* __restrict__ C) {
  const int K = DIN, NC = DHID;
  __shared__ __align__(16) ushort_t As[128 * LDT];
  __shared__ __align__(16) ushort_t Bs[128 * LDT];
  const int tid = threadIdx.x;
  const int bm = blockIdx.x * 128;
  const int bn = blockIdx.y * 128;
  const int row = tid >> 1, half = tid & 1;       // A staging: one 16-elem chunk per thread
  const int arow = bm + row;
  const int wid = tid >> 6, lane = tid & 63;
  const int wr = (wid >> 1) * 64, wc = (wid & 1) * 64;
  const int fr = lane & 15, fg = lane >> 4;
  f32x4 acc[4][4] = {};

  for (int k0 = 0; k0 < K; k0 += 32) {
    // stage A (f32 -> bf16)
    {
      const int p = row * LDT + half * 16;
      if (arow < NN) {
        const float4* src = (const float4*)&A[(size_t)arow * K + k0 + half * 16];
#pragma unroll
        for (int i = 0; i < 4; ++i) {
          float4 v = src[i];
          ushort4 w;
          w.x = f2bf(v.x); w.y = f2bf(v.y); w.z = f2bf(v.z); w.w = f2bf(v.w);
          *(ushort4*)&As[p + i * 4] = w;
        }
      } else {
        ushort4 z = {0, 0, 0, 0};
#pragma unroll
        for (int i = 0; i < 4; ++i) *(ushort4*)&As[p + i * 4] = z;
      }
    }
    // stage B (already bf16, pre-transposed: Bs[col][k])
#pragma unroll
    for (int i = 0; i < 2; ++i) {
      int c2 = tid + i * 256;
      int br = c2 >> 2, bq = c2 & 3;
      uint4 v = *(const uint4*)&Bt[(size_t)(bn + br) * K + k0 + bq * 8];
      *(uint4*)&Bs[br * LDT + bq * 8] = v;
    }
    __syncthreads();
    bf16x8 af[4], bfr[4];
#pragma unroll
    for (int m = 0; m < 4; ++m) af[m] = *(const bf16x8*)&As[(wr + m * 16 + fr) * LDT + fg * 8];
#pragma unroll
    for (int n = 0; n < 4; ++n) bfr[n] = *(const bf16x8*)&Bs[(wc + n * 16 + fr) * LDT + fg * 8];
#pragma unroll
    for (int m = 0; m < 4; ++m)
#pragma unroll
      for (int n = 0; n < 4; ++n)
        acc[m][n] = __builtin_amdgcn_mfma_f32_16x16x32_bf16(af[m], bfr[n], acc[m][n], 0, 0, 0);
    __syncthreads();
  }
#pragma unroll
  for (int m = 0; m < 4; ++m)
#pragma unroll
    for (int n = 0; n < 4; ++n)
#pragma unroll
      for (int j = 0; j < 4; ++j) {
        int r = bm + wr + m * 16 + fg * 4 + j;
        if (r < NN) C[(size_t)r * NC + bn + wc + n * 16 + fr] = acc[m][n][j];
      }
}

// ---------------- MFMA GEMM2: H2 = bf16(relu(concat(OUT1, x[root]))) @ bf16(W2) ----------------
// M=NN, K=1024 (256 from OUT1 + 768 from x[rootn]), N=128.
__global__ __launch_bounds__(256) void k_gemm2m(const float* __restrict__ OUT1,
                                                const float* __restrict__ X,
                                                const int* __restrict__ rootn,
                                                const ushort_t* __restrict__ Bt,
                                                float* __restrict__ C) {
  const int K = DHID + DIN, NC = DOUT;
  __shared__ __align__(16) ushort_t As[128 * LDT];
  __shared__ __align__(16) ushort_t Bs[128 * LDT];
  const int tid = threadIdx.x;
  const int bm = blockIdx.x * 128;
  const int row = tid >> 1, half = tid & 1;
  const int arow = bm + row;
  const int rn = (arow < NN) ? rootn[arow] : 0;
  const int wid = tid >> 6, lane = tid & 63;
  const int wr = (wid >> 1) * 64, wc = (wid & 1) * 64;
  const int fr = lane & 15, fg = lane >> 4;
  f32x4 acc[4][4] = {};

  for (int k0 = 0; k0 < K; k0 += 32) {
    {
      const int p = row * LDT + half * 16;
      const int kk = k0 + half * 16;
      if (arow < NN) {
        const float4* src = (kk < DHID)
            ? (const float4*)&OUT1[(size_t)arow * DHID + kk]
            : (const float4*)&X[(size_t)rn * DIN + (kk - DHID)];
#pragma unroll
        for (int i = 0; i < 4; ++i) {
          float4 v = src[i];
          ushort4 w;
          w.x = f2bf(fmaxf(v.x, 0.f)); w.y = f2bf(fmaxf(v.y, 0.f));
          w.z = f2bf(fmaxf(v.z, 0.f)); w.w = f2bf(fmaxf(v.w, 0.f));
          *(ushort4*)&As[p + i * 4] = w;
        }
      } else {
        ushort4 z = {0, 0, 0, 0};
#pragma unroll
        for (int i = 0; i < 4; ++i) *(ushort4*)&As[p + i * 4] = z;
      }
    }
#pragma unroll
    for (int i = 0; i < 2; ++i) {
      int c2 = tid + i * 256;
      int br = c2 >> 2, bq = c2 & 3;
      uint4 v = *(const uint4*)&Bt[(size_t)br * K + k0 + bq * 8];   // bn==0 (N=128)
      *(uint4*)&Bs[br * LDT + bq * 8] = v;
    }
    __syncthreads();
    bf16x8 af[4], bfr[4];
#pragma unroll
    for (int m = 0; m < 4; ++m) af[m] = *(const bf16x8*)&As[(wr + m * 16 + fr) * LDT + fg * 8];
#pragma unroll
    for (int n = 0; n < 4; ++n) bfr[n] = *(const bf16x8*)&Bs[(wc + n * 16 + fr) * LDT + fg * 8];
#pragma unroll
    for (int m = 0; m < 4; ++m)
#pragma unroll
      for (int n = 0; n < 4; ++n)
        acc[m][n] = __builtin_amdgcn_mfma_f32_16x16x32_bf16(af[m], bfr[n], acc[m][n], 0, 0, 0);
    __syncthreads();
  }
#pragma unroll
  for (int m = 0; m < 4; ++m)
#pragma unroll
    for (int n = 0; n < 4; ++n)
#pragma unroll
      for (int j = 0; j < 4; ++j) {
        int r = bm + wr + m * 16 + fg * 4 + j;
        if (r < NN) C[(size_t)r * NC + wc + n * 16 + fr] = acc[m][n][j];
      }
}

// ---------------- attention scores, layer 1 (D=64, F=256) ----------------
__global__ __launch_bounds__(256) void k_scores1(const float* __restrict__ H,
                                                 const float* __restrict__ att_s,
                                                 const float* __restrict__ att_d,
                                                 float4* __restrict__ as_out,
                                                 float4* __restrict__ ad_out) {
  int lane = threadIdx.x & 63;
  int n = blockIdx.x * 4 + (threadIdx.x >> 6);
  if (n >= NN) return;
  float s[4], d[4];
#pragma unroll
  for (int h = 0; h < 4; ++h) {
    float hv = H[(size_t)n * DHID + h * 64 + lane];
    s[h] = hv * att_s[h * 64 + lane];
    d[h] = hv * att_d[h * 64 + lane];
  }
#pragma unroll
  for (int m = 1; m < 64; m <<= 1) {
#pragma unroll
    for (int h = 0; h < 4; ++h) {
      s[h] += __shfl_xor(s[h], m);
      d[h] += __shfl_xor(d[h], m);
    }
  }
  if (lane == 0) {
    as_out[n] = make_float4(s[0], s[1], s[2], s[3]);
    ad_out[n] = make_float4(d[0], d[1], d[2], d[3]);
  }
}

// ---------------- attention scores, layer 2 (D=32, F=128) ----------------
__global__ __launch_bounds__(256) void k_scores2(const float* __restrict__ H,
                                                 const float* __restrict__ att_s,
                                                 const float* __restrict__ att_d,
                                                 float4* __restrict__ as_out,
                                                 float4* __restrict__ ad_out) {
  int lane = threadIdx.x & 63;
  int n = blockIdx.x * 4 + (threadIdx.x >> 6);
  if (n >= NN) return;
  float s0, s1, d0, d1;
  {
    float hv0 = H[(size_t)n * DOUT + lane];
    float hv1 = H[(size_t)n * DOUT + 64 + lane];
    s0 = hv0 * att_s[lane];       d0 = hv0 * att_d[lane];
    s1 = hv1 * att_s[64 + lane];  d1 = hv1 * att_d[64 + lane];
  }
#pragma unroll
  for (int m = 1; m < 32; m <<= 1) {
    s0 += __shfl_xor(s0, m); s1 += __shfl_xor(s1, m);
    d0 += __shfl_xor(d0, m); d1 += __shfl_xor(d1, m);
  }
  float s0o = __shfl_xor(s0, 32), s1o = __shfl_xor(s1, 32);
  float d0o = __shfl_xor(d0, 32), d1o = __shfl_xor(d1, 32);
  if (lane == 0) {
    as_out[n] = make_float4(s0, s0o, s1, s1o);
    ad_out[n] = make_float4(d0, d0o, d1, d1o);
  }
}

// ---------------- GAT aggregation, layer 1 (heads=4, D=64) ----------------
__global__ __launch_bounds__(256) void k_agg1(const int* __restrict__ off, const int* __restrict__ csr,
                                              const float4* __restrict__ as_v, const float4* __restrict__ ad_v,
                                              const float* __restrict__ H, const float* __restrict__ bias,
                                              float* __restrict__ OUT) {
  int lane = threadIdx.x & 63;
  int n = blockIdx.x * 4 + (threadIdx.x >> 6);
  if (n >= NN) return;
  int beg = off[n], end = off[n + 1];
  float4 adv = ad_v[n];
  float ad_[4] = {adv.x, adv.y, adv.z, adv.w};
  float mx[4] = {-INFINITY, -INFINITY, -INFINITY, -INFINITY};
  for (int e = beg + lane; e < end; e += 64) {
    float4 a = as_v[csr[e]];
    mx[0] = fmaxf(mx[0], a.x); mx[1] = fmaxf(mx[1], a.y);
    mx[2] = fmaxf(mx[2], a.z); mx[3] = fmaxf(mx[3], a.w);
  }
#pragma unroll
  for (int m = 1; m < 64; m <<= 1)
#pragma unroll
    for (int h = 0; h < 4; ++h) mx[h] = fmaxf(mx[h], __shfl_xor(mx[h], m));
  float emax[4];
#pragma unroll
  for (int h = 0; h < 4; ++h) emax[h] = lrelu(mx[h] + ad_[h]);
  float den[4] = {0.f, 0.f, 0.f, 0.f};
  for (int e = beg + lane; e < end; e += 64) {
    float4 a = as_v[csr[e]];
    float aa[4] = {a.x, a.y, a.z, a.w};
#pragma unroll
    for (int h = 0; h < 4; ++h) den[h] += __expf(lrelu(aa[h] + ad_[h]) - emax[h]);
  }
#pragma unroll
  for (int m = 1; m < 64; m <<= 1)
#pragma unroll
    for (int h = 0; h < 4; ++h) den[h] += __shfl_xor(den[h], m);
  float rden[4];
#pragma unroll
  for (int h = 0; h < 4; ++h) rden[h] = 1.f / (den[h] + 1e-16f);
  float acc[4] = {0.f, 0.f, 0.f, 0.f};
  for (int e = beg; e < end; ++e) {
    int s = csr[e];
    float4 a = as_v[s];
    float aa[4] = {a.x, a.y, a.z, a.w};
    float al[4];
#pragma unroll
    for (int h = 0; h < 4; ++h) al[h] = __expf(lrelu(aa[h] + ad_[h]) - emax[h]) * rden[h];
    const float* hr = &H[(size_t)s * DHID];
#pragma unroll
    for (int j = 0; j < 4; ++j) acc[j] += al[j] * hr[j * 64 + lane];
  }
#pragma unroll
  for (int j = 0; j < 4; ++j)
    OUT[(size_t)n * DHID + j * 64 + lane] = acc[j] + bias[j * 64 + lane];
}

// ---------------- GAT aggregation, layer 2 (heads=4, D=32) ----------------
__global__ __launch_bounds__(256) void k_agg2(const int* __restrict__ off, const int* __restrict__ csr,
                                              const float4* __restrict__ as_v, const float4* __restrict__ ad_v,
                                              const float* __restrict__ H, const float* __restrict__ bias,
                                              float* __restrict__ OUT) {
  int lane = threadIdx.x & 63;
  int n = blockIdx.x * 4 + (threadIdx.x >> 6);
  if (n >= NN) return;
  int beg = off[n], end = off[n + 1];
  float4 adv = ad_v[n];
  float ad_[4] = {adv.x, adv.y, adv.z, adv.w};
  float mx[4] = {-INFINITY, -INFINITY, -INFINITY, -INFINITY};
  for (int e = beg + lane; e < end; e += 64) {
    float4 a = as_v[csr[e]];
    mx[0] = fmaxf(mx[0], a.x); mx[1] = fmaxf(mx[1], a.y);
    mx[2] = fmaxf(mx[2], a.z); mx[3] = fmaxf(mx[3], a.w);
  }
#pragma unroll
  for (int m = 1; m < 64; m <<= 1)
#pragma unroll
    for (int h = 0; h < 4; ++h) mx[h] = fmaxf(mx[h], __shfl_xor(mx[h], m));
  float emax[4];
#pragma unroll
  for (int h = 0; h < 4; ++h) emax[h] = lrelu(mx[h] + ad_[h]);
  float den[4] = {0.f, 0.f, 0.f, 0.f};
  for (int e = beg + lane; e < end; e += 64) {
    float4 a = as_v[csr[e]];
    float aa[4] = {a.x, a.y, a.z, a.w};
#pragma unroll
    for (int h = 0; h < 4; ++h) den[h] += __expf(lrelu(aa[h] + ad_[h]) - emax[h]);
  }
#pragma unroll
  for (int m = 1; m < 64; m <<= 1)
#pragma unroll
    for (int h = 0; h < 4; ++h) den[h] += __shfl_xor(den[h], m);
  float rden[4];
#pragma unroll
  for (int h = 0; h < 4; ++h) rden[h] = 1.f / (den[h] + 1e-16f);

  int h0 = lane >> 5;
  float adA = h0 ? ad_[1] : ad_[0];
  float adB = h0 ? ad_[3] : ad_[2];
  float emA = h0 ? emax[1] : emax[0];
  float emB = h0 ? emax[3] : emax[2];
  float rdA = h0 ? rden[1] : rden[0];
  float rdB = h0 ? rden[3] : rden[2];
  float acc0 = 0.f, acc1 = 0.f;
  for (int e = beg; e < end; ++e) {
    int s = csr[e];
    float4 a = as_v[s];
    float aA = h0 ? a.y : a.x;
    float aB = h0 ? a.w : a.z;
    float alA = __expf(lrelu(aA + adA) - emA) * rdA;
    float alB = __expf(lrelu(aB + adB) - emB) * rdB;
    const float* hr = &H[(size_t)s * DOUT];
    acc0 += alA * hr[lane];
    acc1 += alB * hr[64 + lane];
  }
  OUT[(size_t)n * DOUT + lane] = acc0 + bias[lane];
  OUT[(size_t)n * DOUT + 64 + lane] = acc1 + bias[64 + lane];
}

// ---------------- pooling ----------------
__global__ __launch_bounds__(256) void k_pool(const int* __restrict__ segstart,
                                              const float* __restrict__ OUT2,
                                              const float* __restrict__ OUT1,
                                              float* __restrict__ out) {
  int b = blockIdx.x;
  int t = threadIdx.x;
  int s = segstart[b], e = segstart[b + 1];
  float* ob = out + (size_t)b * 384;
  if (s >= e) {
    for (int i = t; i < 384; i += 256) ob[i] = 0.f;
    return;
  }
  if (t < 128) {
    float sum = 0.f;
    for (int n = s; n < e; ++n) {
      float v = OUT2[(size_t)n * DOUT + t];
      sum += v > 0.f ? v : 0.f;
    }
    ob[t] = sum / (float)(e - s);
  } else {
    int k = t - 128;
    ob[128 + k] = OUT1[(size_t)s * DHID + k];
    ob[256 + k] = OUT1[(size_t)s * DHID + 128 + k];
  }
}

// ---------------- launch ----------------
extern "C" void kernel_launch(void* const* d_in, const int* in_sizes, int n_in,
                              void* d_out, int out_size, void* d_ws, size_t ws_size,
                              hipStream_t stream) {
  const float* x    = (const float*)d_in[0];
  const int*   ei   = (const int*)d_in[1];
  const int*   batch = (const int*)d_in[2];
  const float* W1   = (const float*)d_in[3];
  const float* as1w = (const float*)d_in[4];
  const float* ad1w = (const float*)d_in[5];
  const float* b1   = (const float*)d_in[6];
  const float* W2   = (const float*)d_in[7];
  const float* as2w = (const float*)d_in[8];
  const float* ad2w = (const float*)d_in[9];
  const float* b2   = (const float*)d_in[10];
  float* out = (float*)d_out;
  char* ws = (char*)d_ws;

  const int E = in_sizes[1] / 2;
  const int Etot = E + NN;

  // workspace layout (bytes)
  float*  H1   = (float*)(ws + 0);            // NN*256*4 = 51.2 MB (dead after agg1)
  float*  H2   = (float*)(ws + 0);            // NN*128*4 = 25.6 MB (aliases H1[0:25.6M])
  float*  OUT2 = (float*)(ws + 25600000);     // NN*128*4 (aliases H1[25.6:51.2M])
  float*  OUT1 = (float*)(ws + 51200000);     // NN*256*4 = 51.2 MB
  float4* as1  = (float4*)(ws + 102400000);
  float4* ad1  = (float4*)(ws + 103200000);
  float4* as2  = (float4*)(ws + 104000000);
  float4* ad2  = (float4*)(ws + 104800000);
  int* deg     = (int*)(ws + 105600000);      // NN (dead after k_scatter)
  int* cur     = (int*)(ws + 105800000);      // NN (dead after k_scatter)
  int* off     = (int*)(ws + 106000000);      // NN+1
  int* csr     = (int*)(ws + 106200016);      // Etot
  int* segstart = (int*)(ws + 109600016);     // NBGRAPH+1
  int* rootn   = (int*)(ws + 109602080);      // NN
  // bf16 transposed weights, placed in dead regions:
  ushort_t* Wt1b = (ushort_t*)(ws + 105600000);  // 256*768*2 = 393216 B, in deg+cur (dead)
  ushort_t* Wt2b = (ushort_t*)(ws + 25600000);   // 128*1024*2 = 262144 B, in old-H1 region
                                                 // (written after agg1, dead before agg2 writes OUT2)

  const int TB = 256;

  // CSR build + segments
  k_zero2<<<(NN + TB - 1) / TB, TB, 0, stream>>>(deg, cur, NN);
  k_hist<<<(Etot + TB - 1) / TB, TB, 0, stream>>>(ei, deg, E, Etot);
  k_exscan<<<1, 1024, 0, stream>>>(deg, off, NN);
  k_scatter<<<(Etot + TB - 1) / TB, TB, 0, stream>>>(ei, off, cur, csr, E, Etot);
  k_segstart<<<(NBGRAPH + 1 + TB - 1) / TB, TB, 0, stream>>>(batch, segstart, NN, NBGRAPH);
  k_rootn<<<(NN + TB - 1) / TB, TB, 0, stream>>>(batch, segstart, rootn, NN);

  // layer 1
  k_prepW<<<(DIN * DHID + TB - 1) / TB, TB, 0, stream>>>(W1, Wt1b, DIN, DHID);
  dim3 g1((NN + 127) / 128, DHID / 128);
  k_gemm1m<<<g1, TB, 0, stream>>>(x, Wt1b, H1);
  k_scores1<<<(NN + 3) / 4, TB, 0, stream>>>(H1, as1w, ad1w, as1, ad1);
  k_agg1<<<(NN + 3) / 4, TB, 0, stream>>>(off, csr, as1, ad1, H1, b1, OUT1);

  // layer 2 (H1 region dead now; Wt2b + H2 live there)
  k_prepW<<<((DHID + DIN) * DOUT + TB - 1) / TB, TB, 0, stream>>>(W2, Wt2b, DHID + DIN, DOUT);
  dim3 g2((NN + 127) / 128, 1);
  k_gemm2m<<<g2, TB, 0, stream>>>(OUT1, x, rootn, Wt2b, H2);
  k_scores2<<<(NN + 3) / 4, TB, 0, stream>>>(H2, as2w, ad2w, as2, ad2);
  k_agg2<<<(NN + 3) / 4, TB, 0, stream>>>(off, csr, as2, ad2, H2, b2, OUT2);

  // pool
  k_pool<<<NBGRAPH, TB, 0, stream>>>(segstart, OUT2, OUT1, out);
}

// Round 3
// 596.334 us; speedup vs baseline: 1.6438x; 1.0291x over previous
//
#include <hip/hip_runtime.h>

#define NN 50000
#define NBGRAPH 512
#define DIN 768
#define DHID 256
#define DOUT 128

typedef unsigned short ushort_t;
typedef __attribute__((ext_vector_type(8))) short bf16x8;
typedef __attribute__((ext_vector_type(4))) float f32x4;

__device__ __forceinline__ float lrelu(float v) { return v > 0.f ? v : 0.2f * v; }

__device__ __forceinline__ ushort_t f2bf(float f) {
  unsigned int u = __builtin_bit_cast(unsigned int, f);
  u += 0x7fffu + ((u >> 16) & 1u);
  return (ushort_t)(u >> 16);
}
__device__ __forceinline__ float bf2f(ushort_t u) {
  unsigned int x = ((unsigned int)u) << 16;
  return __builtin_bit_cast(float, x);
}

// ---------------- CSR build ----------------
__global__ void k_zero2(int* __restrict__ a, int* __restrict__ b, int n) {
  int i = blockIdx.x * blockDim.x + threadIdx.x;
  if (i < n) { a[i] = 0; b[i] = 0; }
}

__global__ void k_hist(const int* __restrict__ ei, int* __restrict__ deg, int E, int Etot) {
  int e = blockIdx.x * blockDim.x + threadIdx.x;
  if (e >= Etot) return;
  int dst = (e < E) ? ei[e] : (e - E);
  atomicAdd(&deg[dst], 1);
}

// ---- 3-kernel exclusive scan over deg[0..n) -> off, off[n]=total ----
__global__ __launch_bounds__(1024) void k_scan1(const int* __restrict__ deg, int* __restrict__ off,
                                                int* __restrict__ bsum, int n) {
  __shared__ int wsum[16];
  int tid = threadIdx.x, lane = tid & 63, w = tid >> 6;
  int i = blockIdx.x * 1024 + tid;
  int v = (i < n) ? deg[i] : 0;
  int x = v;
#pragma unroll
  for (int d = 1; d < 64; d <<= 1) { int t = __shfl_up(x, d); if (lane >= d) x += t; }
  if (lane == 63) wsum[w] = x;
  __syncthreads();
  if (tid < 16) {
    int y = wsum[tid];
#pragma unroll
    for (int d = 1; d < 16; d <<= 1) { int t = __shfl_up(y, d); if (tid >= d) y += t; }
    wsum[tid] = y;
  }
  __syncthreads();
  int base = (w > 0) ? wsum[w - 1] : 0;
  if (i < n) off[i] = base + x - v;          // block-local exclusive
  if (tid == 1023) bsum[blockIdx.x] = wsum[15];
}

__global__ void k_scan2(int* __restrict__ bsum, int* __restrict__ off, int nb, int n) {
  int lane = threadIdx.x;                     // one wave
  int v = (lane < nb) ? bsum[lane] : 0;
  int x = v;
#pragma unroll
  for (int d = 1; d < 64; d <<= 1) { int t = __shfl_up(x, d); if (lane >= d) x += t; }
  if (lane < nb) bsum[lane] = x - v;          // exclusive
  if (lane == 63) off[n] = x;                 // grand total
}

__global__ void k_scan3(int* __restrict__ off, const int* __restrict__ bsum, int n) {
  int i = blockIdx.x * blockDim.x + threadIdx.x;
  if (i < n) off[i] += bsum[i >> 10];
}

__global__ void k_scatter(const int* __restrict__ ei, const int* __restrict__ off,
                          int* __restrict__ cur, int* __restrict__ csr, int E, int Etot) {
  int e = blockIdx.x * blockDim.x + threadIdx.x;
  if (e >= Etot) return;
  int dst, src;
  if (e < E) { dst = ei[e]; src = ei[E + e]; }
  else       { dst = src = e - E; }
  int p = atomicAdd(&cur[dst], 1);
  csr[off[dst] + p] = src;
}

// ---------------- roots / segments ----------------
__global__ void k_segstart(const int* __restrict__ batch, int* __restrict__ segstart, int n, int b_cnt) {
  int b = blockIdx.x * blockDim.x + threadIdx.x;
  if (b > b_cnt) return;
  int lo = 0, hi = n;
  while (lo < hi) { int mid = (lo + hi) >> 1; if (batch[mid] < b) lo = mid + 1; else hi = mid; }
  segstart[b] = lo;
}

__global__ void k_rootn(const int* __restrict__ batch, const int* __restrict__ segstart,
                        int* __restrict__ rootn, int n) {
  int i = blockIdx.x * blockDim.x + threadIdx.x;
  if (i < n) rootn[i] = segstart[batch[i]];
}

// ---------------- weight transpose+cast: Wt[n][k] = bf16(W[k][n]) ----------------
__global__ void k_prepW(const float* __restrict__ W, ushort_t* __restrict__ Wt, int K, int N) {
  int id = blockIdx.x * blockDim.x + threadIdx.x;
  if (id >= K * N) return;
  int n = id / K, k = id - n * K;
  Wt[(size_t)n * K + k] = f2bf(W[(size_t)k * N + n]);
}

// ---------------- MFMA GEMM1: H1b = bf16( bf16(x) @ bf16(W1) ) ----------------
#define LDT 40
__global__ __launch_bounds__(256) void k_gemm1m(const float* __restrict__ A,
                                                const ushort_t* __restrict__ Bt,
                                                ushort_t* __restrict__ C) {
  const int K = DIN, NC = DHID;
  __shared__ __align__(16) ushort_t As[128 * LDT];
  __shared__ __align__(16) ushort_t Bs[128 * LDT];
  const int tid = threadIdx.x;
  const int bm = blockIdx.x * 128;
  const int bn = blockIdx.y * 128;
  const int row = tid >> 1, half = tid & 1;
  const int arow = bm + row;
  const int wid = tid >> 6, lane = tid & 63;
  const int wr = (wid >> 1) * 64, wc = (wid & 1) * 64;
  const int fr = lane & 15, fg = lane >> 4;
  f32x4 acc[4][4] = {};

  for (int k0 = 0; k0 < K; k0 += 32) {
    {
      const int p = row * LDT + half * 16;
      if (arow < NN) {
        const float4* src = (const float4*)&A[(size_t)arow * K + k0 + half * 16];
#pragma unroll
        for (int i = 0; i < 4; ++i) {
          float4 v = src[i];
          ushort4 w;
          w.x = f2bf(v.x); w.y = f2bf(v.y); w.z = f2bf(v.z); w.w = f2bf(v.w);
          *(ushort4*)&As[p + i * 4] = w;
        }
      } else {
        ushort4 z = {0, 0, 0, 0};
#pragma unroll
        for (int i = 0; i < 4; ++i) *(ushort4*)&As[p + i * 4] = z;
      }
    }
#pragma unroll
    for (int i = 0; i < 2; ++i) {
      int c2 = tid + i * 256;
      int br = c2 >> 2, bq = c2 & 3;
      uint4 v = *(const uint4*)&Bt[(size_t)(bn + br) * K + k0 + bq * 8];
      *(uint4*)&Bs[br * LDT + bq * 8] = v;
    }
    __syncthreads();
    bf16x8 af[4], bfr[4];
#pragma unroll
    for (int m = 0; m < 4; ++m) af[m] = *(const bf16x8*)&As[(wr + m * 16 + fr) * LDT + fg * 8];
#pragma unroll
    for (int n = 0; n < 4; ++n) bfr[n] = *(const bf16x8*)&Bs[(wc + n * 16 + fr) * LDT + fg * 8];
#pragma unroll
    for (int m = 0; m < 4; ++m)
#pragma unroll
      for (int n = 0; n < 4; ++n)
        acc[m][n] = __builtin_amdgcn_mfma_f32_16x16x32_bf16(af[m], bfr[n], acc[m][n], 0, 0, 0);
    __syncthreads();
  }
#pragma unroll
  for (int m = 0; m < 4; ++m)
#pragma unroll
    for (int n = 0; n < 4; ++n)
#pragma unroll
      for (int j = 0; j < 4; ++j) {
        int r = bm + wr + m * 16 + fg * 4 + j;
        if (r < NN) C[(size_t)r * NC + bn + wc + n * 16 + fr] = f2bf(acc[m][n][j]);
      }
}

// ---------------- MFMA GEMM2: H2b = bf16( bf16(relu(concat(OUT1, x[root]))) @ bf16(W2) ) ----------------
__global__ __launch_bounds__(256) void k_gemm2m(const float* __restrict__ OUT1,
                                                const float* __restrict__ X,
                                                const int* __restrict__ rootn,
                                                const ushort_t* __restrict__ Bt,
                                                ushort_t* __restrict__ C) {
  const int K = DHID + DIN, NC = DOUT;
  __shared__ __align__(16) ushort_t As[128 * LDT];
  __shared__ __align__(16) ushort_t Bs[128 * LDT];
  const int tid = threadIdx.x;
  const int bm = blockIdx.x * 128;
  const int row = tid >> 1, half = tid & 1;
  const int arow = bm + row;
  const int rn = (arow < NN) ? rootn[arow] : 0;
  const int wid = tid >> 6, lane = tid & 63;
  const int wr = (wid >> 1) * 64, wc = (wid & 1) * 64;
  const int fr = lane & 15, fg = lane >> 4;
  f32x4 acc[4][4] = {};

  for (int k0 = 0; k0 < K; k0 += 32) {
    {
      const int p = row * LDT + half * 16;
      const int kk = k0 + half * 16;
      if (arow < NN) {
        const float4* src = (kk < DHID)
            ? (const float4*)&OUT1[(size_t)arow * DHID + kk]
            : (const float4*)&X[(size_t)rn * DIN + (kk - DHID)];
#pragma unroll
        for (int i = 0; i < 4; ++i) {
          float4 v = src[i];
          ushort4 w;
          w.x = f2bf(fmaxf(v.x, 0.f)); w.y = f2bf(fmaxf(v.y, 0.f));
          w.z = f2bf(fmaxf(v.z, 0.f)); w.w = f2bf(fmaxf(v.w, 0.f));
          *(ushort4*)&As[p + i * 4] = w;
        }
      } else {
        ushort4 z = {0, 0, 0, 0};
#pragma unroll
        for (int i = 0; i < 4; ++i) *(ushort4*)&As[p + i * 4] = z;
      }
    }
#pragma unroll
    for (int i = 0; i < 2; ++i) {
      int c2 = tid + i * 256;
      int br = c2 >> 2, bq = c2 & 3;
      uint4 v = *(const uint4*)&Bt[(size_t)br * K + k0 + bq * 8];
      *(uint4*)&Bs[br * LDT + bq * 8] = v;
    }
    __syncthreads();
    bf16x8 af[4], bfr[4];
#pragma unroll
    for (int m = 0; m < 4; ++m) af[m] = *(const bf16x8*)&As[(wr + m * 16 + fr) * LDT + fg * 8];
#pragma unroll
    for (int n = 0; n < 4; ++n) bfr[n] = *(const bf16x8*)&Bs[(wc + n * 16 + fr) * LDT + fg * 8];
#pragma unroll
    for (int m = 0; m < 4; ++m)
#pragma unroll
      for (int n = 0; n < 4; ++n)
        acc[m][n] = __builtin_amdgcn_mfma_f32_16x16x32_bf16(af[m], bfr[n], acc[m][n], 0, 0, 0);
    __syncthreads();
  }
#pragma unroll
  for (int m = 0; m < 4; ++m)
#pragma unroll
    for (int n = 0; n < 4; ++n)
#pragma unroll
      for (int j = 0; j < 4; ++j) {
        int r = bm + wr + m * 16 + fg * 4 + j;
        if (r < NN) C[(size_t)r * NC + wc + n * 16 + fr] = f2bf(acc[m][n][j]);
      }
}

// ---------------- attention scores, layer 1 (bf16 H, lane owns feats 4l..4l+3) ----------------
__global__ __launch_bounds__(256) void k_scores1(const ushort_t* __restrict__ Hb,
                                                 const float* __restrict__ att_s,
                                                 const float* __restrict__ att_d,
                                                 float4* __restrict__ as_out,
                                                 float4* __restrict__ ad_out) {
  int lane = threadIdx.x & 63;
  int n = blockIdx.x * 4 + (threadIdx.x >> 6);
  if (n >= NN) return;
  ushort4 hv = *(const ushort4*)&Hb[(size_t)n * DHID + lane * 4];
  float h0 = bf2f(hv.x), h1 = bf2f(hv.y), h2 = bf2f(hv.z), h3 = bf2f(hv.w);
  float4 sa = *(const float4*)&att_s[lane * 4];
  float4 da = *(const float4*)&att_d[lane * 4];
  float ps = h0 * sa.x + h1 * sa.y + h2 * sa.z + h3 * sa.w;
  float pd = h0 * da.x + h1 * da.y + h2 * da.z + h3 * da.w;
#pragma unroll
  for (int m = 1; m < 16; m <<= 1) { ps += __shfl_xor(ps, m); pd += __shfl_xor(pd, m); }
  float4 rs, rd;
  rs.x = __shfl(ps, 0);  rd.x = __shfl(pd, 0);
  rs.y = __shfl(ps, 16); rd.y = __shfl(pd, 16);
  rs.z = __shfl(ps, 32); rd.z = __shfl(pd, 32);
  rs.w = __shfl(ps, 48); rd.w = __shfl(pd, 48);
  if (lane == 0) { as_out[n] = rs; ad_out[n] = rd; }
}

// ---------------- attention scores, layer 2 (bf16 H, lane owns feats 2l,2l+1) ----------------
__global__ __launch_bounds__(256) void k_scores2(const ushort_t* __restrict__ Hb,
                                                 const float* __restrict__ att_s,
                                                 const float* __restrict__ att_d,
                                                 float4* __restrict__ as_out,
                                                 float4* __restrict__ ad_out) {
  int lane = threadIdx.x & 63;
  int n = blockIdx.x * 4 + (threadIdx.x >> 6);
  if (n >= NN) return;
  ushort2 hv = *(const ushort2*)&Hb[(size_t)n * DOUT + lane * 2];
  float h0 = bf2f(hv.x), h1 = bf2f(hv.y);
  float2 sa = *(const float2*)&att_s[lane * 2];
  float2 da = *(const float2*)&att_d[lane * 2];
  float ps = h0 * sa.x + h1 * sa.y;
  float pd = h0 * da.x + h1 * da.y;
#pragma unroll
  for (int m = 1; m < 16; m <<= 1) { ps += __shfl_xor(ps, m); pd += __shfl_xor(pd, m); }
  float4 rs, rd;
  rs.x = __shfl(ps, 0);  rd.x = __shfl(pd, 0);
  rs.y = __shfl(ps, 16); rd.y = __shfl(pd, 16);
  rs.z = __shfl(ps, 32); rd.z = __shfl(pd, 32);
  rs.w = __shfl(ps, 48); rd.w = __shfl(pd, 48);
  if (lane == 0) { as_out[n] = rs; ad_out[n] = rd; }
}

// ---------------- GAT aggregation, layer 1 (bf16 H gather) ----------------
__global__ __launch_bounds__(256) void k_agg1(const int* __restrict__ off, const int* __restrict__ csr,
                                              const float4* __restrict__ as_v, const float4* __restrict__ ad_v,
                                              const ushort_t* __restrict__ Hb, const float* __restrict__ bias,
                                              float* __restrict__ OUT) {
  int lane = threadIdx.x & 63;
  int n = blockIdx.x * 4 + (threadIdx.x >> 6);
  if (n >= NN) return;
  int beg = off[n], end = off[n + 1];
  float4 adv = ad_v[n];
  float ad_[4] = {adv.x, adv.y, adv.z, adv.w};
  float mx[4] = {-INFINITY, -INFINITY, -INFINITY, -INFINITY};
  for (int e = beg + lane; e < end; e += 64) {
    float4 a = as_v[csr[e]];
    mx[0] = fmaxf(mx[0], a.x); mx[1] = fmaxf(mx[1], a.y);
    mx[2] = fmaxf(mx[2], a.z); mx[3] = fmaxf(mx[3], a.w);
  }
#pragma unroll
  for (int m = 1; m < 64; m <<= 1)
#pragma unroll
    for (int h = 0; h < 4; ++h) mx[h] = fmaxf(mx[h], __shfl_xor(mx[h], m));
  float emax[4];
#pragma unroll
  for (int h = 0; h < 4; ++h) emax[h] = lrelu(mx[h] + ad_[h]);
  float den[4] = {0.f, 0.f, 0.f, 0.f};
  for (int e = beg + lane; e < end; e += 64) {
    float4 a = as_v[csr[e]];
    float aa[4] = {a.x, a.y, a.z, a.w};
#pragma unroll
    for (int h = 0; h < 4; ++h) den[h] += __expf(lrelu(aa[h] + ad_[h]) - emax[h]);
  }
#pragma unroll
  for (int m = 1; m < 64; m <<= 1)
#pragma unroll
    for (int h = 0; h < 4; ++h) den[h] += __shfl_xor(den[h], m);
  // per-lane head selection (lane owns features 4*lane .. 4*lane+3, head = lane>>4)
  int h = lane >> 4;
  float adh = (h < 2) ? (h == 0 ? ad_[0] : ad_[1]) : (h == 2 ? ad_[2] : ad_[3]);
  float emh = (h < 2) ? (h == 0 ? emax[0] : emax[1]) : (h == 2 ? emax[2] : emax[3]);
  float dnh = (h < 2) ? (h == 0 ? den[0] : den[1]) : (h == 2 ? den[2] : den[3]);
  float rdh = 1.f / (dnh + 1e-16f);
  float a0 = 0.f, a1 = 0.f, a2 = 0.f, a3 = 0.f;
  for (int e = beg; e < end; ++e) {
    int s = csr[e];
    float4 a = as_v[s];
    float ah = (h < 2) ? (h == 0 ? a.x : a.y) : (h == 2 ? a.z : a.w);
    float al = __expf(lrelu(ah + adh) - emh) * rdh;
    ushort4 hv = *(const ushort4*)&Hb[(size_t)s * DHID + lane * 4];
    a0 += al * bf2f(hv.x); a1 += al * bf2f(hv.y);
    a2 += al * bf2f(hv.z); a3 += al * bf2f(hv.w);
  }
  float4 bv = *(const float4*)&bias[lane * 4];
  *(float4*)&OUT[(size_t)n * DHID + lane * 4] =
      make_float4(a0 + bv.x, a1 + bv.y, a2 + bv.z, a3 + bv.w);
}

// ---------------- GAT aggregation, layer 2 (bf16 H gather) ----------------
__global__ __launch_bounds__(256) void k_agg2(const int* __restrict__ off, const int* __restrict__ csr,
                                              const float4* __restrict__ as_v, const float4* __restrict__ ad_v,
                                              const ushort_t* __restrict__ Hb, const float* __restrict__ bias,
                                              float* __restrict__ OUT) {
  int lane = threadIdx.x & 63;
  int n = blockIdx.x * 4 + (threadIdx.x >> 6);
  if (n >= NN) return;
  int beg = off[n], end = off[n + 1];
  float4 adv = ad_v[n];
  float ad_[4] = {adv.x, adv.y, adv.z, adv.w};
  float mx[4] = {-INFINITY, -INFINITY, -INFINITY, -INFINITY};
  for (int e = beg + lane; e < end; e += 64) {
    float4 a = as_v[csr[e]];
    mx[0] = fmaxf(mx[0], a.x); mx[1] = fmaxf(mx[1], a.y);
    mx[2] = fmaxf(mx[2], a.z); mx[3] = fmaxf(mx[3], a.w);
  }
#pragma unroll
  for (int m = 1; m < 64; m <<= 1)
#pragma unroll
    for (int h = 0; h < 4; ++h) mx[h] = fmaxf(mx[h], __shfl_xor(mx[h], m));
  float emax[4];
#pragma unroll
  for (int h = 0; h < 4; ++h) emax[h] = lrelu(mx[h] + ad_[h]);
  float den[4] = {0.f, 0.f, 0.f, 0.f};
  for (int e = beg + lane; e < end; e += 64) {
    float4 a = as_v[csr[e]];
    float aa[4] = {a.x, a.y, a.z, a.w};
#pragma unroll
    for (int h = 0; h < 4; ++h) den[h] += __expf(lrelu(aa[h] + ad_[h]) - emax[h]);
  }
#pragma unroll
  for (int m = 1; m < 64; m <<= 1)
#pragma unroll
    for (int h = 0; h < 4; ++h) den[h] += __shfl_xor(den[h], m);
  // lane owns features 2*lane, 2*lane+1; head = lane>>4
  int h = lane >> 4;
  float adh = (h < 2) ? (h == 0 ? ad_[0] : ad_[1]) : (h == 2 ? ad_[2] : ad_[3]);
  float emh = (h < 2) ? (h == 0 ? emax[0] : emax[1]) : (h == 2 ? emax[2] : emax[3]);
  float dnh = (h < 2) ? (h == 0 ? den[0] : den[1]) : (h == 2 ? den[2] : den[3]);
  float rdh = 1.f / (dnh + 1e-16f);
  float a0 = 0.f, a1 = 0.f;
  for (int e = beg; e < end; ++e) {
    int s = csr[e];
    float4 a = as_v[s];
    float ah = (h < 2) ? (h == 0 ? a.x : a.y) : (h == 2 ? a.z : a.w);
    float al = __expf(lrelu(ah + adh) - emh) * rdh;
    ushort2 hv = *(const ushort2*)&Hb[(size_t)s * DOUT + lane * 2];
    a0 += al * bf2f(hv.x); a1 += al * bf2f(hv.y);
  }
  float2 bv = *(const float2*)&bias[lane * 2];
  *(float2*)&OUT[(size_t)n * DOUT + lane * 2] = make_float2(a0 + bv.x, a1 + bv.y);
}

// ---------------- pooling ----------------
__global__ __launch_bounds__(256) void k_pool(const int* __restrict__ segstart,
                                              const float* __restrict__ OUT2,
                                              const float* __restrict__ OUT1,
                                              float* __restrict__ out) {
  int b = blockIdx.x;
  int t = threadIdx.x;
  int s = segstart[b], e = segstart[b + 1];
  float* ob = out + (size_t)b * 384;
  if (s >= e) {
    for (int i = t; i < 384; i += 256) ob[i] = 0.f;
    return;
  }
  if (t < 128) {
    float s0 = 0.f, s1 = 0.f;
    int n = s;
    for (; n + 1 < e; n += 2) {
      float v0 = OUT2[(size_t)n * DOUT + t];
      float v1 = OUT2[(size_t)(n + 1) * DOUT + t];
      s0 += fmaxf(v0, 0.f); s1 += fmaxf(v1, 0.f);
    }
    if (n < e) s0 += fmaxf(OUT2[(size_t)n * DOUT + t], 0.f);
    ob[t] = (s0 + s1) / (float)(e - s);
  } else {
    int k = t - 128;
    ob[128 + k] = OUT1[(size_t)s * DHID + k];
    ob[256 + k] = OUT1[(size_t)s * DHID + 128 + k];
  }
}

// ---------------- launch ----------------
extern "C" void kernel_launch(void* const* d_in, const int* in_sizes, int n_in,
                              void* d_out, int out_size, void* d_ws, size_t ws_size,
                              hipStream_t stream) {
  const float* x    = (const float*)d_in[0];
  const int*   ei   = (const int*)d_in[1];
  const int*   batch = (const int*)d_in[2];
  const float* W1   = (const float*)d_in[3];
  const float* as1w = (const float*)d_in[4];
  const float* ad1w = (const float*)d_in[5];
  const float* b1   = (const float*)d_in[6];
  const float* W2   = (const float*)d_in[7];
  const float* as2w = (const float*)d_in[8];
  const float* ad2w = (const float*)d_in[9];
  const float* b2   = (const float*)d_in[10];
  float* out = (float*)d_out;
  char* ws = (char*)d_ws;

  const int E = in_sizes[1] / 2;
  const int Etot = E + NN;

  // workspace layout (bytes)
  ushort_t* H1b = (ushort_t*)(ws + 0);        // NN*256*2 = 25.6 MB (dead after agg1)
  ushort_t* H2b = (ushort_t*)(ws + 0);        // NN*128*2 = 12.8 MB (aliases H1b)
  ushort_t* Wt2b = (ushort_t*)(ws + 13000000);// 128*1024*2 = 262144 B (written after agg1)
  float*  OUT2 = (float*)(ws + 25600000);     // NN*128*4 = 25.6 MB
  float*  OUT1 = (float*)(ws + 51200000);     // NN*256*4 = 51.2 MB
  float4* as1  = (float4*)(ws + 102400000);
  float4* ad1  = (float4*)(ws + 103200000);
  float4* as2  = (float4*)(ws + 104000000);
  float4* ad2  = (float4*)(ws + 104800000);
  int* deg     = (int*)(ws + 105600000);      // NN (dead after scan)
  int* cur     = (int*)(ws + 105800000);      // NN (dead after scatter)
  int* off     = (int*)(ws + 106000000);      // NN+1
  int* csr     = (int*)(ws + 106200016);      // Etot
  int* segstart = (int*)(ws + 109600016);     // NBGRAPH+1
  int* rootn   = (int*)(ws + 109602080);      // NN
  int* bsum    = (int*)(ws + 109802080);      // 49 ints
  ushort_t* Wt1b = (ushort_t*)(ws + 105600000); // 393216 B over deg+cur (dead after scatter)

  const int TB = 256;
  const int NB_SCAN = (NN + 1023) / 1024;

  // CSR build + segments
  k_zero2<<<(NN + TB - 1) / TB, TB, 0, stream>>>(deg, cur, NN);
  k_hist<<<(Etot + TB - 1) / TB, TB, 0, stream>>>(ei, deg, E, Etot);
  k_scan1<<<NB_SCAN, 1024, 0, stream>>>(deg, off, bsum, NN);
  k_scan2<<<1, 64, 0, stream>>>(bsum, off, NB_SCAN, NN);
  k_scan3<<<NB_SCAN, 1024, 0, stream>>>(off, bsum, NN);
  k_scatter<<<(Etot + TB - 1) / TB, TB, 0, stream>>>(ei, off, cur, csr, E, Etot);
  k_segstart<<<(NBGRAPH + 1 + TB - 1) / TB, TB, 0, stream>>>(batch, segstart, NN, NBGRAPH);
  k_rootn<<<(NN + TB - 1) / TB, TB, 0, stream>>>(batch, segstart, rootn, NN);

  // layer 1
  k_prepW<<<(DIN * DHID + TB - 1) / TB, TB, 0, stream>>>(W1, Wt1b, DIN, DHID);
  dim3 g1((NN + 127) / 128, DHID / 128);
  k_gemm1m<<<g1, TB, 0, stream>>>(x, Wt1b, H1b);
  k_scores1<<<(NN + 3) / 4, TB, 0, stream>>>(H1b, as1w, ad1w, as1, ad1);
  k_agg1<<<(NN + 3) / 4, TB, 0, stream>>>(off, csr, as1, ad1, H1b, b1, OUT1);

  // layer 2 (H1b dead now; H2b aliases it)
  k_prepW<<<((DHID + DIN) * DOUT + TB - 1) / TB, TB, 0, stream>>>(W2, Wt2b, DHID + DIN, DOUT);
  dim3 g2((NN + 127) / 128, 1);
  k_gemm2m<<<g2, TB, 0, stream>>>(OUT1, x, rootn, Wt2b, H2b);
  k_scores2<<<(NN + 3) / 4, TB, 0, stream>>>(H2b, as2w, ad2w, as2, ad2);
  k_agg2<<<(NN + 3) / 4, TB, 0, stream>>>(off, csr, as2, ad2, H2b, b2, OUT2);

  // pool
  k_pool<<<NBGRAPH, TB, 0, stream>>>(segstart, OUT2, OUT1, out);
}

// Round 4
// 447.597 us; speedup vs baseline: 2.1901x; 1.3323x over previous
//
#include <hip/hip_runtime.h>

#define NN 50000
#define NBGRAPH 512
#define DIN 768
#define DHID 256
#define DOUT 128

typedef unsigned short ushort_t;
typedef __attribute__((ext_vector_type(8))) short bf16x8;
typedef __attribute__((ext_vector_type(4))) float f32x4;

__device__ __forceinline__ float lrelu(float v) { return v > 0.f ? v : 0.2f * v; }

__device__ __forceinline__ ushort_t f2bf(float f) {
  unsigned int u = __builtin_bit_cast(unsigned int, f);
  u += 0x7fffu + ((u >> 16) & 1u);
  return (ushort_t)(u >> 16);
}
__device__ __forceinline__ float bf2f(ushort_t u) {
  unsigned int x = ((unsigned int)u) << 16;
  return __builtin_bit_cast(float, x);
}

// ---------------- CSR build ----------------
__global__ void k_zero2(int* __restrict__ a, int* __restrict__ b, int n) {
  int i = blockIdx.x * blockDim.x + threadIdx.x;
  if (i < n) { a[i] = 0; b[i] = 0; }
}

__global__ void k_hist(const int* __restrict__ ei, int* __restrict__ deg, int E, int Etot) {
  int e = blockIdx.x * blockDim.x + threadIdx.x;
  if (e >= Etot) return;
  int dst = (e < E) ? ei[e] : (e - E);
  atomicAdd(&deg[dst], 1);
}

// ---- 3-kernel exclusive scan over deg[0..n) -> off, off[n]=total ----
__global__ __launch_bounds__(1024) void k_scan1(const int* __restrict__ deg, int* __restrict__ off,
                                                int* __restrict__ bsum, int n) {
  __shared__ int wsum[16];
  int tid = threadIdx.x, lane = tid & 63, w = tid >> 6;
  int i = blockIdx.x * 1024 + tid;
  int v = (i < n) ? deg[i] : 0;
  int x = v;
#pragma unroll
  for (int d = 1; d < 64; d <<= 1) { int t = __shfl_up(x, d); if (lane >= d) x += t; }
  if (lane == 63) wsum[w] = x;
  __syncthreads();
  if (tid < 16) {
    int y = wsum[tid];
#pragma unroll
    for (int d = 1; d < 16; d <<= 1) { int t = __shfl_up(y, d); if (tid >= d) y += t; }
    wsum[tid] = y;
  }
  __syncthreads();
  int base = (w > 0) ? wsum[w - 1] : 0;
  if (i < n) off[i] = base + x - v;
  if (tid == 1023) bsum[blockIdx.x] = wsum[15];
}

__global__ void k_scan2(int* __restrict__ bsum, int* __restrict__ off, int nb, int n) {
  int lane = threadIdx.x;
  int v = (lane < nb) ? bsum[lane] : 0;
  int x = v;
#pragma unroll
  for (int d = 1; d < 64; d <<= 1) { int t = __shfl_up(x, d); if (lane >= d) x += t; }
  if (lane < nb) bsum[lane] = x - v;
  if (lane == 63) off[n] = x;
}

__global__ void k_scan3(int* __restrict__ off, const int* __restrict__ bsum, int n) {
  int i = blockIdx.x * blockDim.x + threadIdx.x;
  if (i < n) off[i] += bsum[i >> 10];
}

__global__ void k_scatter(const int* __restrict__ ei, const int* __restrict__ off,
                          int* __restrict__ cur, int* __restrict__ csr, int E, int Etot) {
  int e = blockIdx.x * blockDim.x + threadIdx.x;
  if (e >= Etot) return;
  int dst, src;
  if (e < E) { dst = ei[e]; src = ei[E + e]; }
  else       { dst = src = e - E; }
  int p = atomicAdd(&cur[dst], 1);
  csr[off[dst] + p] = src;
}

// ---------------- roots / segments ----------------
__global__ void k_segstart(const int* __restrict__ batch, int* __restrict__ segstart, int n, int b_cnt) {
  int b = blockIdx.x * blockDim.x + threadIdx.x;
  if (b > b_cnt) return;
  int lo = 0, hi = n;
  while (lo < hi) { int mid = (lo + hi) >> 1; if (batch[mid] < b) lo = mid + 1; else hi = mid; }
  segstart[b] = lo;
}

__global__ void k_rootn(const int* __restrict__ batch, const int* __restrict__ segstart,
                        int* __restrict__ rootn, int n) {
  int i = blockIdx.x * blockDim.x + threadIdx.x;
  if (i < n) rootn[i] = segstart[batch[i]];
}

// ---------------- weight transpose+cast: Wt[n][k] = bf16(W[k][n]) ----------------
__global__ void k_prepW(const float* __restrict__ W, ushort_t* __restrict__ Wt, int K, int N) {
  int id = blockIdx.x * blockDim.x + threadIdx.x;
  if (id >= K * N) return;
  int n = id / K, k = id - n * K;
  Wt[(size_t)n * K + k] = f2bf(W[(size_t)k * N + n]);
}

// ---------------- MFMA GEMM1: H1b = bf16( bf16(x) @ bf16(W1) ) ----------------
#define LDT 40
__global__ __launch_bounds__(256) void k_gemm1m(const float* __restrict__ A,
                                                const ushort_t* __restrict__ Bt,
                                                ushort_t* __restrict__ C) {
  const int K = DIN, NC = DHID;
  __shared__ __align__(16) ushort_t As[128 * LDT];
  __shared__ __align__(16) ushort_t Bs[128 * LDT];
  const int tid = threadIdx.x;
  const int bm = blockIdx.x * 128;
  const int bn = blockIdx.y * 128;
  const int row = tid >> 1, half = tid & 1;
  const int arow = bm + row;
  const int wid = tid >> 6, lane = tid & 63;
  const int wr = (wid >> 1) * 64, wc = (wid & 1) * 64;
  const int fr = lane & 15, fg = lane >> 4;
  f32x4 acc[4][4] = {};

  for (int k0 = 0; k0 < K; k0 += 32) {
    {
      const int p = row * LDT + half * 16;
      if (arow < NN) {
        const float4* src = (const float4*)&A[(size_t)arow * K + k0 + half * 16];
#pragma unroll
        for (int i = 0; i < 4; ++i) {
          float4 v = src[i];
          ushort4 w;
          w.x = f2bf(v.x); w.y = f2bf(v.y); w.z = f2bf(v.z); w.w = f2bf(v.w);
          *(ushort4*)&As[p + i * 4] = w;
        }
      } else {
        ushort4 z = {0, 0, 0, 0};
#pragma unroll
        for (int i = 0; i < 4; ++i) *(ushort4*)&As[p + i * 4] = z;
      }
    }
#pragma unroll
    for (int i = 0; i < 2; ++i) {
      int c2 = tid + i * 256;
      int br = c2 >> 2, bq = c2 & 3;
      uint4 v = *(const uint4*)&Bt[(size_t)(bn + br) * K + k0 + bq * 8];
      *(uint4*)&Bs[br * LDT + bq * 8] = v;
    }
    __syncthreads();
    bf16x8 af[4], bfr[4];
#pragma unroll
    for (int m = 0; m < 4; ++m) af[m] = *(const bf16x8*)&As[(wr + m * 16 + fr) * LDT + fg * 8];
#pragma unroll
    for (int n = 0; n < 4; ++n) bfr[n] = *(const bf16x8*)&Bs[(wc + n * 16 + fr) * LDT + fg * 8];
#pragma unroll
    for (int m = 0; m < 4; ++m)
#pragma unroll
      for (int n = 0; n < 4; ++n)
        acc[m][n] = __builtin_amdgcn_mfma_f32_16x16x32_bf16(af[m], bfr[n], acc[m][n], 0, 0, 0);
    __syncthreads();
  }
#pragma unroll
  for (int m = 0; m < 4; ++m)
#pragma unroll
    for (int n = 0; n < 4; ++n)
#pragma unroll
      for (int j = 0; j < 4; ++j) {
        int r = bm + wr + m * 16 + fg * 4 + j;
        if (r < NN) C[(size_t)r * NC + bn + wc + n * 16 + fr] = f2bf(acc[m][n][j]);
      }
}

// ---------------- MFMA GEMM2: H2b = bf16( bf16(relu(concat(OUT1, x[root]))) @ bf16(W2) ) ----------------
__global__ __launch_bounds__(256) void k_gemm2m(const float* __restrict__ OUT1,
                                                const float* __restrict__ X,
                                                const int* __restrict__ rootn,
                                                const ushort_t* __restrict__ Bt,
                                                ushort_t* __restrict__ C) {
  const int K = DHID + DIN, NC = DOUT;
  __shared__ __align__(16) ushort_t As[128 * LDT];
  __shared__ __align__(16) ushort_t Bs[128 * LDT];
  const int tid = threadIdx.x;
  const int bm = blockIdx.x * 128;
  const int row = tid >> 1, half = tid & 1;
  const int arow = bm + row;
  const int rn = (arow < NN) ? rootn[arow] : 0;
  const int wid = tid >> 6, lane = tid & 63;
  const int wr = (wid >> 1) * 64, wc = (wid & 1) * 64;
  const int fr = lane & 15, fg = lane >> 4;
  f32x4 acc[4][4] = {};

  for (int k0 = 0; k0 < K; k0 += 32) {
    {
      const int p = row * LDT + half * 16;
      const int kk = k0 + half * 16;
      if (arow < NN) {
        const float4* src = (kk < DHID)
            ? (const float4*)&OUT1[(size_t)arow * DHID + kk]
            : (const float4*)&X[(size_t)rn * DIN + (kk - DHID)];
#pragma unroll
        for (int i = 0; i < 4; ++i) {
          float4 v = src[i];
          ushort4 w;
          w.x = f2bf(fmaxf(v.x, 0.f)); w.y = f2bf(fmaxf(v.y, 0.f));
          w.z = f2bf(fmaxf(v.z, 0.f)); w.w = f2bf(fmaxf(v.w, 0.f));
          *(ushort4*)&As[p + i * 4] = w;
        }
      } else {
        ushort4 z = {0, 0, 0, 0};
#pragma unroll
        for (int i = 0; i < 4; ++i) *(ushort4*)&As[p + i * 4] = z;
      }
    }
#pragma unroll
    for (int i = 0; i < 2; ++i) {
      int c2 = tid + i * 256;
      int br = c2 >> 2, bq = c2 & 3;
      uint4 v = *(const uint4*)&Bt[(size_t)br * K + k0 + bq * 8];
      *(uint4*)&Bs[br * LDT + bq * 8] = v;
    }
    __syncthreads();
    bf16x8 af[4], bfr[4];
#pragma unroll
    for (int m = 0; m < 4; ++m) af[m] = *(const bf16x8*)&As[(wr + m * 16 + fr) * LDT + fg * 8];
#pragma unroll
    for (int n = 0; n < 4; ++n) bfr[n] = *(const bf16x8*)&Bs[(wc + n * 16 + fr) * LDT + fg * 8];
#pragma unroll
    for (int m = 0; m < 4; ++m)
#pragma unroll
      for (int n = 0; n < 4; ++n)
        acc[m][n] = __builtin_amdgcn_mfma_f32_16x16x32_bf16(af[m], bfr[n], acc[m][n], 0, 0, 0);
    __syncthreads();
  }
#pragma unroll
  for (int m = 0; m < 4; ++m)
#pragma unroll
    for (int n = 0; n < 4; ++n)
#pragma unroll
      for (int j = 0; j < 4; ++j) {
        int r = bm + wr + m * 16 + fg * 4 + j;
        if (r < NN) C[(size_t)r * NC + wc + n * 16 + fr] = f2bf(acc[m][n][j]);
      }
}

// ---------------- attention scores, layer 1 ----------------
__global__ __launch_bounds__(256) void k_scores1(const ushort_t* __restrict__ Hb,
                                                 const float* __restrict__ att_s,
                                                 const float* __restrict__ att_d,
                                                 float4* __restrict__ as_out,
                                                 float4* __restrict__ ad_out) {
  int lane = threadIdx.x & 63;
  int n = blockIdx.x * 4 + (threadIdx.x >> 6);
  if (n >= NN) return;
  ushort4 hv = *(const ushort4*)&Hb[(size_t)n * DHID + lane * 4];
  float h0 = bf2f(hv.x), h1 = bf2f(hv.y), h2 = bf2f(hv.z), h3 = bf2f(hv.w);
  float4 sa = *(const float4*)&att_s[lane * 4];
  float4 da = *(const float4*)&att_d[lane * 4];
  float ps = h0 * sa.x + h1 * sa.y + h2 * sa.z + h3 * sa.w;
  float pd = h0 * da.x + h1 * da.y + h2 * da.z + h3 * da.w;
#pragma unroll
  for (int m = 1; m < 16; m <<= 1) { ps += __shfl_xor(ps, m); pd += __shfl_xor(pd, m); }
  float4 rs, rd;
  rs.x = __shfl(ps, 0);  rd.x = __shfl(pd, 0);
  rs.y = __shfl(ps, 16); rd.y = __shfl(pd, 16);
  rs.z = __shfl(ps, 32); rd.z = __shfl(pd, 32);
  rs.w = __shfl(ps, 48); rd.w = __shfl(pd, 48);
  if (lane == 0) { as_out[n] = rs; ad_out[n] = rd; }
}

// ---------------- attention scores, layer 2 ----------------
__global__ __launch_bounds__(256) void k_scores2(const ushort_t* __restrict__ Hb,
                                                 const float* __restrict__ att_s,
                                                 const float* __restrict__ att_d,
                                                 float4* __restrict__ as_out,
                                                 float4* __restrict__ ad_out) {
  int lane = threadIdx.x & 63;
  int n = blockIdx.x * 4 + (threadIdx.x >> 6);
  if (n >= NN) return;
  ushort2 hv = *(const ushort2*)&Hb[(size_t)n * DOUT + lane * 2];
  float h0 = bf2f(hv.x), h1 = bf2f(hv.y);
  float2 sa = *(const float2*)&att_s[lane * 2];
  float2 da = *(const float2*)&att_d[lane * 2];
  float ps = h0 * sa.x + h1 * sa.y;
  float pd = h0 * da.x + h1 * da.y;
#pragma unroll
  for (int m = 1; m < 16; m <<= 1) { ps += __shfl_xor(ps, m); pd += __shfl_xor(pd, m); }
  float4 rs, rd;
  rs.x = __shfl(ps, 0);  rd.x = __shfl(pd, 0);
  rs.y = __shfl(ps, 16); rd.y = __shfl(pd, 16);
  rs.z = __shfl(ps, 32); rd.z = __shfl(pd, 32);
  rs.w = __shfl(ps, 48); rd.w = __shfl(pd, 48);
  if (lane == 0) { as_out[n] = rs; ad_out[n] = rd; }
}

__device__ __forceinline__ void fma8(float* acc, float al, bf16x8 v) {
#pragma unroll
  for (int q = 0; q < 8; ++q) acc[q] += al * bf2f((ushort_t)v[q]);
}

// ---------------- GAT aggregation, layer 1 (4 edge-slots x 16 lanes x 16 feats) ----------------
__global__ __launch_bounds__(256) void k_agg1(const int* __restrict__ off, const int* __restrict__ csr,
                                              const float4* __restrict__ as_v, const float4* __restrict__ ad_v,
                                              const ushort_t* __restrict__ Hb, const float* __restrict__ bias,
                                              float* __restrict__ OUT) {
  int lane = threadIdx.x & 63;
  int n = blockIdx.x * 4 + (threadIdx.x >> 6);
  if (n >= NN) return;
  int beg = off[n], end = off[n + 1];
  float4 adv = ad_v[n];
  float ad_[4] = {adv.x, adv.y, adv.z, adv.w};
  float mx[4] = {-INFINITY, -INFINITY, -INFINITY, -INFINITY};
  for (int e = beg + lane; e < end; e += 64) {
    float4 a = as_v[csr[e]];
    mx[0] = fmaxf(mx[0], a.x); mx[1] = fmaxf(mx[1], a.y);
    mx[2] = fmaxf(mx[2], a.z); mx[3] = fmaxf(mx[3], a.w);
  }
#pragma unroll
  for (int m = 1; m < 64; m <<= 1)
#pragma unroll
    for (int h = 0; h < 4; ++h) mx[h] = fmaxf(mx[h], __shfl_xor(mx[h], m));
  float emax[4];
#pragma unroll
  for (int h = 0; h < 4; ++h) emax[h] = lrelu(mx[h] + ad_[h]);
  float den[4] = {0.f, 0.f, 0.f, 0.f};
  for (int e = beg + lane; e < end; e += 64) {
    float4 a = as_v[csr[e]];
    float aa[4] = {a.x, a.y, a.z, a.w};
#pragma unroll
    for (int h = 0; h < 4; ++h) den[h] += __expf(lrelu(aa[h] + ad_[h]) - emax[h]);
  }
#pragma unroll
  for (int m = 1; m < 64; m <<= 1)
#pragma unroll
    for (int h = 0; h < 4; ++h) den[h] += __shfl_xor(den[h], m);

  // pass C: slot = lane>>4 handles edges beg+slot, beg+slot+4, ...
  // lane (slot, j=lane&15) owns features [16j, 16j+16) -> head h = j>>2
  const int slot = lane >> 4, j = lane & 15;
  const int h = j >> 2;
  float adh = (h & 2) ? ((h & 1) ? ad_[3] : ad_[2]) : ((h & 1) ? ad_[1] : ad_[0]);
  float emh = (h & 2) ? ((h & 1) ? emax[3] : emax[2]) : ((h & 1) ? emax[1] : emax[0]);
  float dnh = (h & 2) ? ((h & 1) ? den[3] : den[2]) : ((h & 1) ? den[1] : den[0]);
  float rdh = 1.f / (dnh + 1e-16f);
  float acc[16] = {};
  for (int eb = beg; eb < end; eb += 4) {
    int e = eb + slot;
    if (e < end) {
      int s = csr[e];
      float4 a = as_v[s];
      float ah = (h & 2) ? ((h & 1) ? a.w : a.z) : ((h & 1) ? a.y : a.x);
      float al = __expf(lrelu(ah + adh) - emh) * rdh;
      const ushort_t* hr = &Hb[(size_t)s * DHID + j * 16];
      bf16x8 v0 = *(const bf16x8*)&hr[0];
      bf16x8 v1 = *(const bf16x8*)&hr[8];
      fma8(acc, al, v0);
      fma8(acc + 8, al, v1);
    }
  }
  // reduce the 4 slots (fixed order -> deterministic)
#pragma unroll
  for (int q = 0; q < 16; ++q) {
    acc[q] += __shfl_xor(acc[q], 16);
    acc[q] += __shfl_xor(acc[q], 32);
  }
  // lane (slot, j) writes features [16j + 4*slot, +4)
  float o[4];
#pragma unroll
  for (int k = 0; k < 4; ++k) {
    float alo = (slot & 1) ? acc[4 + k] : acc[k];
    float ahi = (slot & 1) ? acc[12 + k] : acc[8 + k];
    o[k] = (slot & 2) ? ahi : alo;
  }
  float4 bv = *(const float4*)&bias[j * 16 + slot * 4];
  *(float4*)&OUT[(size_t)n * DHID + j * 16 + slot * 4] =
      make_float4(o[0] + bv.x, o[1] + bv.y, o[2] + bv.z, o[3] + bv.w);
}

// ---------------- GAT aggregation, layer 2 (4 edge-slots x 16 lanes x 8 feats) ----------------
__global__ __launch_bounds__(256) void k_agg2(const int* __restrict__ off, const int* __restrict__ csr,
                                              const float4* __restrict__ as_v, const float4* __restrict__ ad_v,
                                              const ushort_t* __restrict__ Hb, const float* __restrict__ bias,
                                              float* __restrict__ OUT) {
  int lane = threadIdx.x & 63;
  int n = blockIdx.x * 4 + (threadIdx.x >> 6);
  if (n >= NN) return;
  int beg = off[n], end = off[n + 1];
  float4 adv = ad_v[n];
  float ad_[4] = {adv.x, adv.y, adv.z, adv.w};
  float mx[4] = {-INFINITY, -INFINITY, -INFINITY, -INFINITY};
  for (int e = beg + lane; e < end; e += 64) {
    float4 a = as_v[csr[e]];
    mx[0] = fmaxf(mx[0], a.x); mx[1] = fmaxf(mx[1], a.y);
    mx[2] = fmaxf(mx[2], a.z); mx[3] = fmaxf(mx[3], a.w);
  }
#pragma unroll
  for (int m = 1; m < 64; m <<= 1)
#pragma unroll
    for (int h = 0; h < 4; ++h) mx[h] = fmaxf(mx[h], __shfl_xor(mx[h], m));
  float emax[4];
#pragma unroll
  for (int h = 0; h < 4; ++h) emax[h] = lrelu(mx[h] + ad_[h]);
  float den[4] = {0.f, 0.f, 0.f, 0.f};
  for (int e = beg + lane; e < end; e += 64) {
    float4 a = as_v[csr[e]];
    float aa[4] = {a.x, a.y, a.z, a.w};
#pragma unroll
    for (int h = 0; h < 4; ++h) den[h] += __expf(lrelu(aa[h] + ad_[h]) - emax[h]);
  }
#pragma unroll
  for (int m = 1; m < 64; m <<= 1)
#pragma unroll
    for (int h = 0; h < 4; ++h) den[h] += __shfl_xor(den[h], m);

  // pass C: slot = lane>>4; lane (slot, j) owns features [8j, 8j+8) -> head j>>2
  const int slot = lane >> 4, j = lane & 15;
  const int h = j >> 2;
  float adh = (h & 2) ? ((h & 1) ? ad_[3] : ad_[2]) : ((h & 1) ? ad_[1] : ad_[0]);
  float emh = (h & 2) ? ((h & 1) ? emax[3] : emax[2]) : ((h & 1) ? emax[1] : emax[0]);
  float dnh = (h & 2) ? ((h & 1) ? den[3] : den[2]) : ((h & 1) ? den[1] : den[0]);
  float rdh = 1.f / (dnh + 1e-16f);
  float acc[8] = {};
  for (int eb = beg; eb < end; eb += 4) {
    int e = eb + slot;
    if (e < end) {
      int s = csr[e];
      float4 a = as_v[s];
      float ah = (h & 2) ? ((h & 1) ? a.w : a.z) : ((h & 1) ? a.y : a.x);
      float al = __expf(lrelu(ah + adh) - emh) * rdh;
      bf16x8 v0 = *(const bf16x8*)&Hb[(size_t)s * DOUT + j * 8];
      fma8(acc, al, v0);
    }
  }
#pragma unroll
  for (int q = 0; q < 8; ++q) {
    acc[q] += __shfl_xor(acc[q], 16);
    acc[q] += __shfl_xor(acc[q], 32);
  }
  // lane (slot, j) writes features [8j + 2*slot, +2)
  float o0 = (slot & 2) ? ((slot & 1) ? acc[6] : acc[4]) : ((slot & 1) ? acc[2] : acc[0]);
  float o1 = (slot & 2) ? ((slot & 1) ? acc[7] : acc[5]) : ((slot & 1) ? acc[3] : acc[1]);
  float2 bv = *(const float2*)&bias[j * 8 + slot * 2];
  *(float2*)&OUT[(size_t)n * DOUT + j * 8 + slot * 2] = make_float2(o0 + bv.x, o1 + bv.y);
}

// ---------------- pooling ----------------
__global__ __launch_bounds__(256) void k_pool(const int* __restrict__ segstart,
                                              const float* __restrict__ OUT2,
                                              const float* __restrict__ OUT1,
                                              float* __restrict__ out) {
  int b = blockIdx.x;
  int t = threadIdx.x;
  int s = segstart[b], e = segstart[b + 1];
  float* ob = out + (size_t)b * 384;
  if (s >= e) {
    for (int i = t; i < 384; i += 256) ob[i] = 0.f;
    return;
  }
  if (t < 128) {
    float s0 = 0.f, s1 = 0.f;
    int n = s;
    for (; n + 1 < e; n += 2) {
      float v0 = OUT2[(size_t)n * DOUT + t];
      float v1 = OUT2[(size_t)(n + 1) * DOUT + t];
      s0 += fmaxf(v0, 0.f); s1 += fmaxf(v1, 0.f);
    }
    if (n < e) s0 += fmaxf(OUT2[(size_t)n * DOUT + t], 0.f);
    ob[t] = (s0 + s1) / (float)(e - s);
  } else {
    int k = t - 128;
    ob[128 + k] = OUT1[(size_t)s * DHID + k];
    ob[256 + k] = OUT1[(size_t)s * DHID + 128 + k];
  }
}

// ---------------- launch ----------------
extern "C" void kernel_launch(void* const* d_in, const int* in_sizes, int n_in,
                              void* d_out, int out_size, void* d_ws, size_t ws_size,
                              hipStream_t stream) {
  const float* x    = (const float*)d_in[0];
  const int*   ei   = (const int*)d_in[1];
  const int*   batch = (const int*)d_in[2];
  const float* W1   = (const float*)d_in[3];
  const float* as1w = (const float*)d_in[4];
  const float* ad1w = (const float*)d_in[5];
  const float* b1   = (const float*)d_in[6];
  const float* W2   = (const float*)d_in[7];
  const float* as2w = (const float*)d_in[8];
  const float* ad2w = (const float*)d_in[9];
  const float* b2   = (const float*)d_in[10];
  float* out = (float*)d_out;
  char* ws = (char*)d_ws;

  const int E = in_sizes[1] / 2;
  const int Etot = E + NN;

  // workspace layout (bytes)
  ushort_t* H1b = (ushort_t*)(ws + 0);        // NN*256*2 = 25.6 MB (dead after agg1)
  ushort_t* H2b = (ushort_t*)(ws + 0);        // NN*128*2 = 12.8 MB (aliases H1b)
  ushort_t* Wt2b = (ushort_t*)(ws + 13000000);// 262144 B (written after agg1)
  float*  OUT2 = (float*)(ws + 25600000);     // NN*128*4 = 25.6 MB
  float*  OUT1 = (float*)(ws + 51200000);     // NN*256*4 = 51.2 MB
  float4* as1  = (float4*)(ws + 102400000);
  float4* ad1  = (float4*)(ws + 103200000);
  float4* as2  = (float4*)(ws + 104000000);
  float4* ad2  = (float4*)(ws + 104800000);
  int* deg     = (int*)(ws + 105600000);      // NN (dead after scan)
  int* cur     = (int*)(ws + 105800000);      // NN (dead after scatter)
  int* off     = (int*)(ws + 106000000);      // NN+1
  int* csr     = (int*)(ws + 106200016);      // Etot
  int* segstart = (int*)(ws + 109600016);     // NBGRAPH+1
  int* rootn   = (int*)(ws + 109602080);      // NN
  int* bsum    = (int*)(ws + 109802080);      // 49 ints
  ushort_t* Wt1b = (ushort_t*)(ws + 105600000); // 393216 B over deg+cur (dead after scatter)

  const int TB = 256;
  const int NB_SCAN = (NN + 1023) / 1024;

  // CSR build + segments
  k_zero2<<<(NN + TB - 1) / TB, TB, 0, stream>>>(deg, cur, NN);
  k_hist<<<(Etot + TB - 1) / TB, TB, 0, stream>>>(ei, deg, E, Etot);
  k_scan1<<<NB_SCAN, 1024, 0, stream>>>(deg, off, bsum, NN);
  k_scan2<<<1, 64, 0, stream>>>(bsum, off, NB_SCAN, NN);
  k_scan3<<<NB_SCAN, 1024, 0, stream>>>(off, bsum, NN);
  k_scatter<<<(Etot + TB - 1) / TB, TB, 0, stream>>>(ei, off, cur, csr, E, Etot);
  k_segstart<<<(NBGRAPH + 1 + TB - 1) / TB, TB, 0, stream>>>(batch, segstart, NN, NBGRAPH);
  k_rootn<<<(NN + TB - 1) / TB, TB, 0, stream>>>(batch, segstart, rootn, NN);

  // layer 1
  k_prepW<<<(DIN * DHID + TB - 1) / TB, TB, 0, stream>>>(W1, Wt1b, DIN, DHID);
  dim3 g1((NN + 127) / 128, DHID / 128);
  k_gemm1m<<<g1, TB, 0, stream>>>(x, Wt1b, H1b);
  k_scores1<<<(NN + 3) / 4, TB, 0, stream>>>(H1b, as1w, ad1w, as1, ad1);
  k_agg1<<<(NN + 3) / 4, TB, 0, stream>>>(off, csr, as1, ad1, H1b, b1, OUT1);

  // layer 2 (H1b dead now; H2b aliases it)
  k_prepW<<<((DHID + DIN) * DOUT + TB - 1) / TB, TB, 0, stream>>>(W2, Wt2b, DHID + DIN, DOUT);
  dim3 g2((NN + 127) / 128, 1);
  k_gemm2m<<<g2, TB, 0, stream>>>(OUT1, x, rootn, Wt2b, H2b);
  k_scores2<<<(NN + 3) / 4, TB, 0, stream>>>(H2b, as2w, ad2w, as2, ad2);
  k_agg2<<<(NN + 3) / 4, TB, 0, stream>>>(off, csr, as2, ad2, H2b, b2, OUT2);

  // pool
  k_pool<<<NBGRAPH, TB, 0, stream>>>(segstart, OUT2, OUT1, out);
}

// Round 5
// 428.589 us; speedup vs baseline: 2.2872x; 1.0444x over previous
//
#include <hip/hip_runtime.h>

#define NN 50000
#define NBGRAPH 512
#define DIN 768
#define DHID 256
#define DOUT 128

typedef unsigned short ushort_t;
typedef __attribute__((ext_vector_type(8))) short bf16x8;
typedef __attribute__((ext_vector_type(4))) float f32x4;

__device__ __forceinline__ float lrelu(float v) { return v > 0.f ? v : 0.2f * v; }

__device__ __forceinline__ ushort_t f2bf(float f) {
  unsigned int u = __builtin_bit_cast(unsigned int, f);
  u += 0x7fffu + ((u >> 16) & 1u);
  return (ushort_t)(u >> 16);
}
__device__ __forceinline__ float bf2f(ushort_t u) {
  unsigned int x = ((unsigned int)u) << 16;
  return __builtin_bit_cast(float, x);
}

// ---------------- CSR build ----------------
__global__ void k_zero2(int* __restrict__ a, int* __restrict__ b, int n) {
  int i = blockIdx.x * blockDim.x + threadIdx.x;
  if (i < n) { a[i] = 0; b[i] = 0; }
}

__global__ void k_hist(const int* __restrict__ ei, int* __restrict__ deg, int E, int Etot) {
  int e = blockIdx.x * blockDim.x + threadIdx.x;
  if (e >= Etot) return;
  int dst = (e < E) ? ei[e] : (e - E);
  atomicAdd(&deg[dst], 1);
}

// ---- 3-kernel exclusive scan ----
__global__ __launch_bounds__(1024) void k_scan1(const int* __restrict__ deg, int* __restrict__ off,
                                                int* __restrict__ bsum, int n) {
  __shared__ int wsum[16];
  int tid = threadIdx.x, lane = tid & 63, w = tid >> 6;
  int i = blockIdx.x * 1024 + tid;
  int v = (i < n) ? deg[i] : 0;
  int x = v;
#pragma unroll
  for (int d = 1; d < 64; d <<= 1) { int t = __shfl_up(x, d); if (lane >= d) x += t; }
  if (lane == 63) wsum[w] = x;
  __syncthreads();
  if (tid < 16) {
    int y = wsum[tid];
#pragma unroll
    for (int d = 1; d < 16; d <<= 1) { int t = __shfl_up(y, d); if (tid >= d) y += t; }
    wsum[tid] = y;
  }
  __syncthreads();
  int base = (w > 0) ? wsum[w - 1] : 0;
  if (i < n) off[i] = base + x - v;
  if (tid == 1023) bsum[blockIdx.x] = wsum[15];
}

__global__ void k_scan2(int* __restrict__ bsum, int* __restrict__ off, int nb, int n) {
  int lane = threadIdx.x;
  int v = (lane < nb) ? bsum[lane] : 0;
  int x = v;
#pragma unroll
  for (int d = 1; d < 64; d <<= 1) { int t = __shfl_up(x, d); if (lane >= d) x += t; }
  if (lane < nb) bsum[lane] = x - v;
  if (lane == 63) off[n] = x;
}

__global__ void k_scan3(int* __restrict__ off, const int* __restrict__ bsum, int n) {
  int i = blockIdx.x * blockDim.x + threadIdx.x;
  if (i < n) off[i] += bsum[i >> 10];
}

__global__ void k_scatter(const int* __restrict__ ei, const int* __restrict__ off,
                          int* __restrict__ cur, int* __restrict__ csr, int E, int Etot) {
  int e = blockIdx.x * blockDim.x + threadIdx.x;
  if (e >= Etot) return;
  int dst, src;
  if (e < E) { dst = ei[e]; src = ei[E + e]; }
  else       { dst = src = e - E; }
  int p = atomicAdd(&cur[dst], 1);
  csr[off[dst] + p] = src;
}

// ---------------- roots / segments ----------------
__global__ void k_segstart(const int* __restrict__ batch, int* __restrict__ segstart, int n, int b_cnt) {
  int b = blockIdx.x * blockDim.x + threadIdx.x;
  if (b > b_cnt) return;
  int lo = 0, hi = n;
  while (lo < hi) { int mid = (lo + hi) >> 1; if (batch[mid] < b) lo = mid + 1; else hi = mid; }
  segstart[b] = lo;
}

__global__ void k_rootn(const int* __restrict__ batch, const int* __restrict__ segstart,
                        int* __restrict__ rootn, int n) {
  int i = blockIdx.x * blockDim.x + threadIdx.x;
  if (i < n) rootn[i] = segstart[batch[i]];
}

// ---------------- weight transpose+cast ----------------
__global__ void k_prepW(const float* __restrict__ W, ushort_t* __restrict__ Wt, int K, int N) {
  int id = blockIdx.x * blockDim.x + threadIdx.x;
  if (id >= K * N) return;
  int n = id / K, k = id - n * K;
  Wt[(size_t)n * K + k] = f2bf(W[(size_t)k * N + n]);
}

// ---------------- MFMA GEMM1 ----------------
#define LDT 40
__global__ __launch_bounds__(256) void k_gemm1m(const float* __restrict__ A,
                                                const ushort_t* __restrict__ Bt,
                                                ushort_t* __restrict__ C) {
  const int K = DIN, NC = DHID;
  __shared__ __align__(16) ushort_t As[128 * LDT];
  __shared__ __align__(16) ushort_t Bs[128 * LDT];
  const int tid = threadIdx.x;
  const int bm = blockIdx.x * 128;
  const int bn = blockIdx.y * 128;
  const int row = tid >> 1, half = tid & 1;
  const int arow = bm + row;
  const int wid = tid >> 6, lane = tid & 63;
  const int wr = (wid >> 1) * 64, wc = (wid & 1) * 64;
  const int fr = lane & 15, fg = lane >> 4;
  f32x4 acc[4][4] = {};

  for (int k0 = 0; k0 < K; k0 += 32) {
    {
      const int p = row * LDT + half * 16;
      if (arow < NN) {
        const float4* src = (const float4*)&A[(size_t)arow * K + k0 + half * 16];
#pragma unroll
        for (int i = 0; i < 4; ++i) {
          float4 v = src[i];
          ushort4 w;
          w.x = f2bf(v.x); w.y = f2bf(v.y); w.z = f2bf(v.z); w.w = f2bf(v.w);
          *(ushort4*)&As[p + i * 4] = w;
        }
      } else {
        ushort4 z = {0, 0, 0, 0};
#pragma unroll
        for (int i = 0; i < 4; ++i) *(ushort4*)&As[p + i * 4] = z;
      }
    }
#pragma unroll
    for (int i = 0; i < 2; ++i) {
      int c2 = tid + i * 256;
      int br = c2 >> 2, bq = c2 & 3;
      uint4 v = *(const uint4*)&Bt[(size_t)(bn + br) * K + k0 + bq * 8];
      *(uint4*)&Bs[br * LDT + bq * 8] = v;
    }
    __syncthreads();
    bf16x8 af[4], bfr[4];
#pragma unroll
    for (int m = 0; m < 4; ++m) af[m] = *(const bf16x8*)&As[(wr + m * 16 + fr) * LDT + fg * 8];
#pragma unroll
    for (int n = 0; n < 4; ++n) bfr[n] = *(const bf16x8*)&Bs[(wc + n * 16 + fr) * LDT + fg * 8];
#pragma unroll
    for (int m = 0; m < 4; ++m)
#pragma unroll
      for (int n = 0; n < 4; ++n)
        acc[m][n] = __builtin_amdgcn_mfma_f32_16x16x32_bf16(af[m], bfr[n], acc[m][n], 0, 0, 0);
    __syncthreads();
  }
#pragma unroll
  for (int m = 0; m < 4; ++m)
#pragma unroll
    for (int n = 0; n < 4; ++n)
#pragma unroll
      for (int j = 0; j < 4; ++j) {
        int r = bm + wr + m * 16 + fg * 4 + j;
        if (r < NN) C[(size_t)r * NC + bn + wc + n * 16 + fr] = f2bf(acc[m][n][j]);
      }
}

// ---------------- MFMA GEMM2 ----------------
__global__ __launch_bounds__(256) void k_gemm2m(const float* __restrict__ OUT1,
                                                const float* __restrict__ X,
                                                const int* __restrict__ rootn,
                                                const ushort_t* __restrict__ Bt,
                                                ushort_t* __restrict__ C) {
  const int K = DHID + DIN, NC = DOUT;
  __shared__ __align__(16) ushort_t As[128 * LDT];
  __shared__ __align__(16) ushort_t Bs[128 * LDT];
  const int tid = threadIdx.x;
  const int bm = blockIdx.x * 128;
  const int row = tid >> 1, half = tid & 1;
  const int arow = bm + row;
  const int rn = (arow < NN) ? rootn[arow] : 0;
  const int wid = tid >> 6, lane = tid & 63;
  const int wr = (wid >> 1) * 64, wc = (wid & 1) * 64;
  const int fr = lane & 15, fg = lane >> 4;
  f32x4 acc[4][4] = {};

  for (int k0 = 0; k0 < K; k0 += 32) {
    {
      const int p = row * LDT + half * 16;
      const int kk = k0 + half * 16;
      if (arow < NN) {
        const float4* src = (kk < DHID)
            ? (const float4*)&OUT1[(size_t)arow * DHID + kk]
            : (const float4*)&X[(size_t)rn * DIN + (kk - DHID)];
#pragma unroll
        for (int i = 0; i < 4; ++i) {
          float4 v = src[i];
          ushort4 w;
          w.x = f2bf(fmaxf(v.x, 0.f)); w.y = f2bf(fmaxf(v.y, 0.f));
          w.z = f2bf(fmaxf(v.z, 0.f)); w.w = f2bf(fmaxf(v.w, 0.f));
          *(ushort4*)&As[p + i * 4] = w;
        }
      } else {
        ushort4 z = {0, 0, 0, 0};
#pragma unroll
        for (int i = 0; i < 4; ++i) *(ushort4*)&As[p + i * 4] = z;
      }
    }
#pragma unroll
    for (int i = 0; i < 2; ++i) {
      int c2 = tid + i * 256;
      int br = c2 >> 2, bq = c2 & 3;
      uint4 v = *(const uint4*)&Bt[(size_t)br * K + k0 + bq * 8];
      *(uint4*)&Bs[br * LDT + bq * 8] = v;
    }
    __syncthreads();
    bf16x8 af[4], bfr[4];
#pragma unroll
    for (int m = 0; m < 4; ++m) af[m] = *(const bf16x8*)&As[(wr + m * 16 + fr) * LDT + fg * 8];
#pragma unroll
    for (int n = 0; n < 4; ++n) bfr[n] = *(const bf16x8*)&Bs[(wc + n * 16 + fr) * LDT + fg * 8];
#pragma unroll
    for (int m = 0; m < 4; ++m)
#pragma unroll
      for (int n = 0; n < 4; ++n)
        acc[m][n] = __builtin_amdgcn_mfma_f32_16x16x32_bf16(af[m], bfr[n], acc[m][n], 0, 0, 0);
    __syncthreads();
  }
#pragma unroll
  for (int m = 0; m < 4; ++m)
#pragma unroll
    for (int n = 0; n < 4; ++n)
#pragma unroll
      for (int j = 0; j < 4; ++j) {
        int r = bm + wr + m * 16 + fg * 4 + j;
        if (r < NN) C[(size_t)r * NC + wc + n * 16 + fr] = f2bf(acc[m][n][j]);
      }
}

// ---------------- attention scores ----------------
__global__ __launch_bounds__(256) void k_scores1(const ushort_t* __restrict__ Hb,
                                                 const float* __restrict__ att_s,
                                                 const float* __restrict__ att_d,
                                                 float4* __restrict__ as_out,
                                                 float4* __restrict__ ad_out) {
  int lane = threadIdx.x & 63;
  int n = blockIdx.x * 4 + (threadIdx.x >> 6);
  if (n >= NN) return;
  ushort4 hv = *(const ushort4*)&Hb[(size_t)n * DHID + lane * 4];
  float h0 = bf2f(hv.x), h1 = bf2f(hv.y), h2 = bf2f(hv.z), h3 = bf2f(hv.w);
  float4 sa = *(const float4*)&att_s[lane * 4];
  float4 da = *(const float4*)&att_d[lane * 4];
  float ps = h0 * sa.x + h1 * sa.y + h2 * sa.z + h3 * sa.w;
  float pd = h0 * da.x + h1 * da.y + h2 * da.z + h3 * da.w;
#pragma unroll
  for (int m = 1; m < 16; m <<= 1) { ps += __shfl_xor(ps, m); pd += __shfl_xor(pd, m); }
  float4 rs, rd;
  rs.x = __shfl(ps, 0);  rd.x = __shfl(pd, 0);
  rs.y = __shfl(ps, 16); rd.y = __shfl(pd, 16);
  rs.z = __shfl(ps, 32); rd.z = __shfl(pd, 32);
  rs.w = __shfl(ps, 48); rd.w = __shfl(pd, 48);
  if (lane == 0) { as_out[n] = rs; ad_out[n] = rd; }
}

__global__ __launch_bounds__(256) void k_scores2(const ushort_t* __restrict__ Hb,
                                                 const float* __restrict__ att_s,
                                                 const float* __restrict__ att_d,
                                                 float4* __restrict__ as_out,
                                                 float4* __restrict__ ad_out) {
  int lane = threadIdx.x & 63;
  int n = blockIdx.x * 4 + (threadIdx.x >> 6);
  if (n >= NN) return;
  ushort2 hv = *(const ushort2*)&Hb[(size_t)n * DOUT + lane * 2];
  float h0 = bf2f(hv.x), h1 = bf2f(hv.y);
  float2 sa = *(const float2*)&att_s[lane * 2];
  float2 da = *(const float2*)&att_d[lane * 2];
  float ps = h0 * sa.x + h1 * sa.y;
  float pd = h0 * da.x + h1 * da.y;
#pragma unroll
  for (int m = 1; m < 16; m <<= 1) { ps += __shfl_xor(ps, m); pd += __shfl_xor(pd, m); }
  float4 rs, rd;
  rs.x = __shfl(ps, 0);  rd.x = __shfl(pd, 0);
  rs.y = __shfl(ps, 16); rd.y = __shfl(pd, 16);
  rs.z = __shfl(ps, 32); rd.z = __shfl(pd, 32);
  rs.w = __shfl(ps, 48); rd.w = __shfl(pd, 48);
  if (lane == 0) { as_out[n] = rs; ad_out[n] = rd; }
}

__device__ __forceinline__ void fma8(float* acc, float al, bf16x8 v) {
#pragma unroll
  for (int q = 0; q < 8; ++q) acc[q] += al * bf2f((ushort_t)v[q]);
}

__device__ __forceinline__ float sel_h(int h, float q0, float q1, float q2, float q3) {
  float lo = (h & 1) ? q1 : q0;
  float hi = (h & 1) ? q3 : q2;
  return (h & 2) ? hi : lo;
}

// ---------------- GAT aggregation, layer 1 ----------------
// fast path (deg<=64): cache csr + finished alphas in regs; pass C pulls via bpermute,
// only the Hb-row gather stays global, software-pipelined one iteration ahead.
__global__ __launch_bounds__(256) void k_agg1(const int* __restrict__ off, const int* __restrict__ csr,
                                              const float4* __restrict__ as_v, const float4* __restrict__ ad_v,
                                              const ushort_t* __restrict__ Hb, const float* __restrict__ bias,
                                              float* __restrict__ OUT) {
  int lane = threadIdx.x & 63;
  int n = blockIdx.x * 4 + (threadIdx.x >> 6);
  if (n >= NN) return;
  int beg = off[n], end = off[n + 1];
  int nt = end - beg;
  float4 adv = ad_v[n];
  float ad_[4] = {adv.x, adv.y, adv.z, adv.w};
  const int slot = lane >> 4, j = lane & 15;
  const int h = j >> 2;

  if (nt <= 64) {
    bool have = lane < nt;
    int s_l = csr[beg + (have ? lane : 0)];
    float4 a_l = as_v[s_l];
    // pass A: masked max
    float mx[4];
    mx[0] = have ? a_l.x : -INFINITY; mx[1] = have ? a_l.y : -INFINITY;
    mx[2] = have ? a_l.z : -INFINITY; mx[3] = have ? a_l.w : -INFINITY;
#pragma unroll
    for (int m = 1; m < 64; m <<= 1)
#pragma unroll
      for (int q = 0; q < 4; ++q) mx[q] = fmaxf(mx[q], __shfl_xor(mx[q], m));
    float emax[4];
#pragma unroll
    for (int q = 0; q < 4; ++q) emax[q] = lrelu(mx[q] + ad_[q]);
    // pass B: per-lane exp, wave sum
    float p0 = have ? __expf(lrelu(a_l.x + ad_[0]) - emax[0]) : 0.f;
    float p1 = have ? __expf(lrelu(a_l.y + ad_[1]) - emax[1]) : 0.f;
    float p2 = have ? __expf(lrelu(a_l.z + ad_[2]) - emax[2]) : 0.f;
    float p3 = have ? __expf(lrelu(a_l.w + ad_[3]) - emax[3]) : 0.f;
    float d0 = p0, d1 = p1, d2 = p2, d3 = p3;
#pragma unroll
    for (int m = 1; m < 64; m <<= 1) {
      d0 += __shfl_xor(d0, m); d1 += __shfl_xor(d1, m);
      d2 += __shfl_xor(d2, m); d3 += __shfl_xor(d3, m);
    }
    // finished per-edge alphas in regs
    p0 *= 1.f / (d0 + 1e-16f); p1 *= 1.f / (d1 + 1e-16f);
    p2 *= 1.f / (d2 + 1e-16f); p3 *= 1.f / (d3 + 1e-16f);

    // pass C, pipelined
    float acc[16] = {};
    int src = slot;
    int sP = __shfl(s_l, src);
    float alP;
    {
      float q0 = __shfl(p0, src), q1 = __shfl(p1, src), q2 = __shfl(p2, src), q3 = __shfl(p3, src);
      alP = (src < nt) ? sel_h(h, q0, q1, q2, q3) : 0.f;
    }
    const ushort_t* hrP = &Hb[(size_t)sP * DHID + j * 16];
    bf16x8 v0 = *(const bf16x8*)&hrP[0];
    bf16x8 v1 = *(const bf16x8*)&hrP[8];
    for (int eb = 0; eb < nt; eb += 4) {
      int srcn = (eb + 4 + slot) & 63;
      int sN = __shfl(s_l, srcn);
      float q0 = __shfl(p0, srcn), q1 = __shfl(p1, srcn), q2 = __shfl(p2, srcn), q3 = __shfl(p3, srcn);
      float alN = (eb + 4 + slot < nt) ? sel_h(h, q0, q1, q2, q3) : 0.f;
      const ushort_t* hrN = &Hb[(size_t)sN * DHID + j * 16];
      bf16x8 n0 = *(const bf16x8*)&hrN[0];
      bf16x8 n1 = *(const bf16x8*)&hrN[8];
      fma8(acc, alP, v0);
      fma8(acc + 8, alP, v1);
      alP = alN; v0 = n0; v1 = n1;
    }
#pragma unroll
    for (int q = 0; q < 16; ++q) {
      acc[q] += __shfl_xor(acc[q], 16);
      acc[q] += __shfl_xor(acc[q], 32);
    }
    float o[4];
#pragma unroll
    for (int k = 0; k < 4; ++k) {
      float alo = (slot & 1) ? acc[4 + k] : acc[k];
      float ahi = (slot & 1) ? acc[12 + k] : acc[8 + k];
      o[k] = (slot & 2) ? ahi : alo;
    }
    float4 bv = *(const float4*)&bias[j * 16 + slot * 4];
    *(float4*)&OUT[(size_t)n * DHID + j * 16 + slot * 4] =
        make_float4(o[0] + bv.x, o[1] + bv.y, o[2] + bv.z, o[3] + bv.w);
    return;
  }

  // ---- slow path (deg > 64): round-4 code ----
  float mx[4] = {-INFINITY, -INFINITY, -INFINITY, -INFINITY};
  for (int e = beg + lane; e < end; e += 64) {
    float4 a = as_v[csr[e]];
    mx[0] = fmaxf(mx[0], a.x); mx[1] = fmaxf(mx[1], a.y);
    mx[2] = fmaxf(mx[2], a.z); mx[3] = fmaxf(mx[3], a.w);
  }
#pragma unroll
  for (int m = 1; m < 64; m <<= 1)
#pragma unroll
    for (int q = 0; q < 4; ++q) mx[q] = fmaxf(mx[q], __shfl_xor(mx[q], m));
  float emax[4];
#pragma unroll
  for (int q = 0; q < 4; ++q) emax[q] = lrelu(mx[q] + ad_[q]);
  float den[4] = {0.f, 0.f, 0.f, 0.f};
  for (int e = beg + lane; e < end; e += 64) {
    float4 a = as_v[csr[e]];
    float aa[4] = {a.x, a.y, a.z, a.w};
#pragma unroll
    for (int q = 0; q < 4; ++q) den[q] += __expf(lrelu(aa[q] + ad_[q]) - emax[q]);
  }
#pragma unroll
  for (int m = 1; m < 64; m <<= 1)
#pragma unroll
    for (int q = 0; q < 4; ++q) den[q] += __shfl_xor(den[q], m);
  float adh = sel_h(h, ad_[0], ad_[1], ad_[2], ad_[3]);
  float emh = sel_h(h, emax[0], emax[1], emax[2], emax[3]);
  float dnh = sel_h(h, den[0], den[1], den[2], den[3]);
  float rdh = 1.f / (dnh + 1e-16f);
  float acc[16] = {};
  for (int eb = beg; eb < end; eb += 4) {
    int e = eb + slot;
    if (e < end) {
      int s = csr[e];
      float4 a = as_v[s];
      float ah = sel_h(h, a.x, a.y, a.z, a.w);
      float al = __expf(lrelu(ah + adh) - emh) * rdh;
      const ushort_t* hr = &Hb[(size_t)s * DHID + j * 16];
      bf16x8 v0 = *(const bf16x8*)&hr[0];
      bf16x8 v1 = *(const bf16x8*)&hr[8];
      fma8(acc, al, v0);
      fma8(acc + 8, al, v1);
    }
  }
#pragma unroll
  for (int q = 0; q < 16; ++q) {
    acc[q] += __shfl_xor(acc[q], 16);
    acc[q] += __shfl_xor(acc[q], 32);
  }
  float o[4];
#pragma unroll
  for (int k = 0; k < 4; ++k) {
    float alo = (slot & 1) ? acc[4 + k] : acc[k];
    float ahi = (slot & 1) ? acc[12 + k] : acc[8 + k];
    o[k] = (slot & 2) ? ahi : alo;
  }
  float4 bv = *(const float4*)&bias[j * 16 + slot * 4];
  *(float4*)&OUT[(size_t)n * DHID + j * 16 + slot * 4] =
      make_float4(o[0] + bv.x, o[1] + bv.y, o[2] + bv.z, o[3] + bv.w);
}

// ---------------- GAT aggregation, layer 2 ----------------
__global__ __launch_bounds__(256) void k_agg2(const int* __restrict__ off, const int* __restrict__ csr,
                                              const float4* __restrict__ as_v, const float4* __restrict__ ad_v,
                                              const ushort_t* __restrict__ Hb, const float* __restrict__ bias,
                                              float* __restrict__ OUT) {
  int lane = threadIdx.x & 63;
  int n = blockIdx.x * 4 + (threadIdx.x >> 6);
  if (n >= NN) return;
  int beg = off[n], end = off[n + 1];
  int nt = end - beg;
  float4 adv = ad_v[n];
  float ad_[4] = {adv.x, adv.y, adv.z, adv.w};
  const int slot = lane >> 4, j = lane & 15;
  const int h = j >> 2;

  if (nt <= 64) {
    bool have = lane < nt;
    int s_l = csr[beg + (have ? lane : 0)];
    float4 a_l = as_v[s_l];
    float mx[4];
    mx[0] = have ? a_l.x : -INFINITY; mx[1] = have ? a_l.y : -INFINITY;
    mx[2] = have ? a_l.z : -INFINITY; mx[3] = have ? a_l.w : -INFINITY;
#pragma unroll
    for (int m = 1; m < 64; m <<= 1)
#pragma unroll
      for (int q = 0; q < 4; ++q) mx[q] = fmaxf(mx[q], __shfl_xor(mx[q], m));
    float emax[4];
#pragma unroll
    for (int q = 0; q < 4; ++q) emax[q] = lrelu(mx[q] + ad_[q]);
    float p0 = have ? __expf(lrelu(a_l.x + ad_[0]) - emax[0]) : 0.f;
    float p1 = have ? __expf(lrelu(a_l.y + ad_[1]) - emax[1]) : 0.f;
    float p2 = have ? __expf(lrelu(a_l.z + ad_[2]) - emax[2]) : 0.f;
    float p3 = have ? __expf(lrelu(a_l.w + ad_[3]) - emax[3]) : 0.f;
    float d0 = p0, d1 = p1, d2 = p2, d3 = p3;
#pragma unroll
    for (int m = 1; m < 64; m <<= 1) {
      d0 += __shfl_xor(d0, m); d1 += __shfl_xor(d1, m);
      d2 += __shfl_xor(d2, m); d3 += __shfl_xor(d3, m);
    }
    p0 *= 1.f / (d0 + 1e-16f); p1 *= 1.f / (d1 + 1e-16f);
    p2 *= 1.f / (d2 + 1e-16f); p3 *= 1.f / (d3 + 1e-16f);

    float acc[8] = {};
    int src = slot;
    int sP = __shfl(s_l, src);
    float alP;
    {
      float q0 = __shfl(p0, src), q1 = __shfl(p1, src), q2 = __shfl(p2, src), q3 = __shfl(p3, src);
      alP = (src < nt) ? sel_h(h, q0, q1, q2, q3) : 0.f;
    }
    bf16x8 v0 = *(const bf16x8*)&Hb[(size_t)sP * DOUT + j * 8];
    for (int eb = 0; eb < nt; eb += 4) {
      int srcn = (eb + 4 + slot) & 63;
      int sN = __shfl(s_l, srcn);
      float q0 = __shfl(p0, srcn), q1 = __shfl(p1, srcn), q2 = __shfl(p2, srcn), q3 = __shfl(p3, srcn);
      float alN = (eb + 4 + slot < nt) ? sel_h(h, q0, q1, q2, q3) : 0.f;
      bf16x8 n0 = *(const bf16x8*)&Hb[(size_t)sN * DOUT + j * 8];
      fma8(acc, alP, v0);
      alP = alN; v0 = n0;
    }
#pragma unroll
    for (int q = 0; q < 8; ++q) {
      acc[q] += __shfl_xor(acc[q], 16);
      acc[q] += __shfl_xor(acc[q], 32);
    }
    float o0 = (slot & 2) ? ((slot & 1) ? acc[6] : acc[4]) : ((slot & 1) ? acc[2] : acc[0]);
    float o1 = (slot & 2) ? ((slot & 1) ? acc[7] : acc[5]) : ((slot & 1) ? acc[3] : acc[1]);
    float2 bv = *(const float2*)&bias[j * 8 + slot * 2];
    *(float2*)&OUT[(size_t)n * DOUT + j * 8 + slot * 2] = make_float2(o0 + bv.x, o1 + bv.y);
    return;
  }

  // slow path
  float mx[4] = {-INFINITY, -INFINITY, -INFINITY, -INFINITY};
  for (int e = beg + lane; e < end; e += 64) {
    float4 a = as_v[csr[e]];
    mx[0] = fmaxf(mx[0], a.x); mx[1] = fmaxf(mx[1], a.y);
    mx[2] = fmaxf(mx[2], a.z); mx[3] = fmaxf(mx[3], a.w);
  }
#pragma unroll
  for (int m = 1; m < 64; m <<= 1)
#pragma unroll
    for (int q = 0; q < 4; ++q) mx[q] = fmaxf(mx[q], __shfl_xor(mx[q], m));
  float emax[4];
#pragma unroll
  for (int q = 0; q < 4; ++q) emax[q] = lrelu(mx[q] + ad_[q]);
  float den[4] = {0.f, 0.f, 0.f, 0.f};
  for (int e = beg + lane; e < end; e += 64) {
    float4 a = as_v[csr[e]];
    float aa[4] = {a.x, a.y, a.z, a.w};
#pragma unroll
    for (int q = 0; q < 4; ++q) den[q] += __expf(lrelu(aa[q] + ad_[q]) - emax[q]);
  }
#pragma unroll
  for (int m = 1; m < 64; m <<= 1)
#pragma unroll
    for (int q = 0; q < 4; ++q) den[q] += __shfl_xor(den[q], m);
  float adh = sel_h(h, ad_[0], ad_[1], ad_[2], ad_[3]);
  float emh = sel_h(h, emax[0], emax[1], emax[2], emax[3]);
  float dnh = sel_h(h, den[0], den[1], den[2], den[3]);
  float rdh = 1.f / (dnh + 1e-16f);
  float acc[8] = {};
  for (int eb = beg; eb < end; eb += 4) {
    int e = eb + slot;
    if (e < end) {
      int s = csr[e];
      float4 a = as_v[s];
      float ah = sel_h(h, a.x, a.y, a.z, a.w);
      float al = __expf(lrelu(ah + adh) - emh) * rdh;
      bf16x8 v0 = *(const bf16x8*)&Hb[(size_t)s * DOUT + j * 8];
      fma8(acc, al, v0);
    }
  }
#pragma unroll
  for (int q = 0; q < 8; ++q) {
    acc[q] += __shfl_xor(acc[q], 16);
    acc[q] += __shfl_xor(acc[q], 32);
  }
  float o0 = (slot & 2) ? ((slot & 1) ? acc[6] : acc[4]) : ((slot & 1) ? acc[2] : acc[0]);
  float o1 = (slot & 2) ? ((slot & 1) ? acc[7] : acc[5]) : ((slot & 1) ? acc[3] : acc[1]);
  float2 bv = *(const float2*)&bias[j * 8 + slot * 2];
  *(float2*)&OUT[(size_t)n * DOUT + j * 8 + slot * 2] = make_float2(o0 + bv.x, o1 + bv.y);
}

// ---------------- pooling ----------------
__global__ __launch_bounds__(256) void k_pool(const int* __restrict__ segstart,
                                              const float* __restrict__ OUT2,
                                              const float* __restrict__ OUT1,
                                              float* __restrict__ out) {
  int b = blockIdx.x;
  int t = threadIdx.x;
  int s = segstart[b], e = segstart[b + 1];
  float* ob = out + (size_t)b * 384;
  if (s >= e) {
    for (int i = t; i < 384; i += 256) ob[i] = 0.f;
    return;
  }
  if (t < 128) {
    float s0 = 0.f, s1 = 0.f;
    int n = s;
    for (; n + 1 < e; n += 2) {
      float v0 = OUT2[(size_t)n * DOUT + t];
      float v1 = OUT2[(size_t)(n + 1) * DOUT + t];
      s0 += fmaxf(v0, 0.f); s1 += fmaxf(v1, 0.f);
    }
    if (n < e) s0 += fmaxf(OUT2[(size_t)n * DOUT + t], 0.f);
    ob[t] = (s0 + s1) / (float)(e - s);
  } else {
    int k = t - 128;
    ob[128 + k] = OUT1[(size_t)s * DHID + k];
    ob[256 + k] = OUT1[(size_t)s * DHID + 128 + k];
  }
}

// ---------------- launch ----------------
extern "C" void kernel_launch(void* const* d_in, const int* in_sizes, int n_in,
                              void* d_out, int out_size, void* d_ws, size_t ws_size,
                              hipStream_t stream) {
  const float* x    = (const float*)d_in[0];
  const int*   ei   = (const int*)d_in[1];
  const int*   batch = (const int*)d_in[2];
  const float* W1   = (const float*)d_in[3];
  const float* as1w = (const float*)d_in[4];
  const float* ad1w = (const float*)d_in[5];
  const float* b1   = (const float*)d_in[6];
  const float* W2   = (const float*)d_in[7];
  const float* as2w = (const float*)d_in[8];
  const float* ad2w = (const float*)d_in[9];
  const float* b2   = (const float*)d_in[10];
  float* out = (float*)d_out;
  char* ws = (char*)d_ws;

  const int E = in_sizes[1] / 2;
  const int Etot = E + NN;

  // workspace layout (bytes)
  ushort_t* H1b = (ushort_t*)(ws + 0);
  ushort_t* H2b = (ushort_t*)(ws + 0);
  ushort_t* Wt2b = (ushort_t*)(ws + 13000000);
  float*  OUT2 = (float*)(ws + 25600000);
  float*  OUT1 = (float*)(ws + 51200000);
  float4* as1  = (float4*)(ws + 102400000);
  float4* ad1  = (float4*)(ws + 103200000);
  float4* as2  = (float4*)(ws + 104000000);
  float4* ad2  = (float4*)(ws + 104800000);
  int* deg     = (int*)(ws + 105600000);
  int* cur     = (int*)(ws + 105800000);
  int* off     = (int*)(ws + 106000000);
  int* csr     = (int*)(ws + 106200016);
  int* segstart = (int*)(ws + 109600016);
  int* rootn   = (int*)(ws + 109602080);
  int* bsum    = (int*)(ws + 109802080);
  ushort_t* Wt1b = (ushort_t*)(ws + 105600000);

  const int TB = 256;
  const int NB_SCAN = (NN + 1023) / 1024;

  k_zero2<<<(NN + TB - 1) / TB, TB, 0, stream>>>(deg, cur, NN);
  k_hist<<<(Etot + TB - 1) / TB, TB, 0, stream>>>(ei, deg, E, Etot);
  k_scan1<<<NB_SCAN, 1024, 0, stream>>>(deg, off, bsum, NN);
  k_scan2<<<1, 64, 0, stream>>>(bsum, off, NB_SCAN, NN);
  k_scan3<<<NB_SCAN, 1024, 0, stream>>>(off, bsum, NN);
  k_scatter<<<(Etot + TB - 1) / TB, TB, 0, stream>>>(ei, off, cur, csr, E, Etot);
  k_segstart<<<(NBGRAPH + 1 + TB - 1) / TB, TB, 0, stream>>>(batch, segstart, NN, NBGRAPH);
  k_rootn<<<(NN + TB - 1) / TB, TB, 0, stream>>>(batch, segstart, rootn, NN);

  k_prepW<<<(DIN * DHID + TB - 1) / TB, TB, 0, stream>>>(W1, Wt1b, DIN, DHID);
  dim3 g1((NN + 127) / 128, DHID / 128);
  k_gemm1m<<<g1, TB, 0, stream>>>(x, Wt1b, H1b);
  k_scores1<<<(NN + 3) / 4, TB, 0, stream>>>(H1b, as1w, ad1w, as1, ad1);
  k_agg1<<<(NN + 3) / 4, TB, 0, stream>>>(off, csr, as1, ad1, H1b, b1, OUT1);

  k_prepW<<<((DHID + DIN) * DOUT + TB - 1) / TB, TB, 0, stream>>>(W2, Wt2b, DHID + DIN, DOUT);
  dim3 g2((NN + 127) / 128, 1);
  k_gemm2m<<<g2, TB, 0, stream>>>(OUT1, x, rootn, Wt2b, H2b);
  k_scores2<<<(NN + 3) / 4, TB, 0, stream>>>(H2b, as2w, ad2w, as2, ad2);
  k_agg2<<<(NN + 3) / 4, TB, 0, stream>>>(off, csr, as2, ad2, H2b, b2, OUT2);

  k_pool<<<NBGRAPH, TB, 0, stream>>>(segstart, OUT2, OUT1, out);
}